// Round 4
// baseline (2364.751 us; speedup 1.0000x reference)
//
#include <hip/hip_runtime.h>
#include <cstddef>
#include <cstdint>
#include <cmath>

#define TS 4096   // spatial size H*W (64*64)
#define CD 384    // channels
#define NHEADS 8
#define CPH 48    // channels per head

// ---------------------------------------------------------------------------
// FP64-accumulating GEMM for 1x1 conv (per batch): O[m,s] = sum_k W[m,k]X[k,s]
// X,W fp32 inputs; O double. Tile 64(m)x128(n), K-step 16, 256 thr, 4x8 micro.
// M must be a multiple of 64; grid = (S/128, M/64).
// ---------------------------------------------------------------------------
__global__ __launch_bounds__(256)
void gemm_f64(const float* __restrict__ X, const float* __restrict__ W,
              const float* __restrict__ bias, double* __restrict__ O,
              int K, int M, int S, int relu)
{
    const int m0 = blockIdx.y * 64;
    const int n0 = blockIdx.x * 128;
    const int t  = threadIdx.x;

    __shared__ float As[16][68];
    __shared__ float Bs[16][136];

    const int tm = t >> 4;      // 0..15 -> m block of 4
    const int tn = t & 15;      // 0..15 -> n block of 8

    double acc[4][8] = {};

    for (int k0 = 0; k0 < K; k0 += 16) {
        {   // A: 64 m x 16 k ; thread -> m = t>>2, kq = (t&3)*4
            const int m = t >> 2, kq = (t & 3) * 4;
            const float4 v = *(const float4*)(W + (size_t)(m0 + m) * K + k0 + kq);
            As[kq + 0][m] = v.x; As[kq + 1][m] = v.y;
            As[kq + 2][m] = v.z; As[kq + 3][m] = v.w;
        }
        {   // B: 16 k x 128 n ; thread -> k = t>>4, n8 = (t&15)*8
            const int k = t >> 4, n8 = (t & 15) * 8;
            const float* src = X + (size_t)(k0 + k) * S + n0 + n8;
            float4 v0 = *(const float4*)(src);
            float4 v1 = *(const float4*)(src + 4);
            *(float4*)&Bs[k][n8]     = v0;
            *(float4*)&Bs[k][n8 + 4] = v1;
        }
        __syncthreads();

        #pragma unroll
        for (int k = 0; k < 16; k++) {
            const float4 a4  = *(const float4*)&As[k][tm * 4];
            const float4 b40 = *(const float4*)&Bs[k][tn * 8];
            const float4 b41 = *(const float4*)&Bs[k][tn * 8 + 4];
            const double a[4]  = {(double)a4.x, (double)a4.y, (double)a4.z, (double)a4.w};
            const double bb[8] = {(double)b40.x, (double)b40.y, (double)b40.z, (double)b40.w,
                                  (double)b41.x, (double)b41.y, (double)b41.z, (double)b41.w};
            #pragma unroll
            for (int i = 0; i < 4; i++)
                #pragma unroll
                for (int j = 0; j < 8; j++)
                    acc[i][j] += a[i] * bb[j];
        }
        __syncthreads();
    }

    #pragma unroll
    for (int i = 0; i < 4; i++) {
        const int m = m0 + tm * 4 + i;
        const double bv = bias ? (double)bias[m] : 0.0;
        double* dst = O + (size_t)m * S + n0 + tn * 8;
        #pragma unroll
        for (int j = 0; j < 8; j++) {
            double v = acc[i][j] + bv;
            if (relu && v < 0.0) v = 0.0;
            dst[j] = v;
        }
    }
}

// ---------------------------------------------------------------------------
// Depthwise 3x3 SAME on fp64 input plane [384][4096]; rounds result to fp32.
// grid (16, 384) per batch.
// ---------------------------------------------------------------------------
__global__ __launch_bounds__(256)
void dwq_f64(const double* __restrict__ X, const float* __restrict__ Wd,
             float* __restrict__ O)
{
    const int c = blockIdx.y;
    const int s = blockIdx.x * 256 + threadIdx.x;
    const int yy0 = s >> 6, xx0 = s & 63;
    const double* Xc = X + (size_t)c * TS;
    const float* w = Wd + (size_t)c * 9;
    double acc = 0.0;
    #pragma unroll
    for (int dy = -1; dy <= 1; dy++) {
        const int yy = yy0 + dy;
        if (yy < 0 || yy > 63) continue;
        #pragma unroll
        for (int dx = -1; dx <= 1; dx++) {
            const int xx = xx0 + dx;
            if (xx < 0 || xx > 63) continue;
            acc += Xc[yy * 64 + xx] * (double)w[(dy + 1) * 3 + (dx + 1)];
        }
    }
    O[(size_t)c * TS + s] = (float)acc;
}

// ---------------------------------------------------------------------------
// Gate stage 2 on fp64 g1 plane [192][4096]: sigmoid dot, deterministic sums.
// grid 16 per batch; caller offsets `partial` by b*16.
// ---------------------------------------------------------------------------
__global__ __launch_bounds__(256)
void gate2p_f64(const double* __restrict__ G, const float* __restrict__ Wg2,
                const float* __restrict__ bg2, double* __restrict__ partial)
{
    const int s = blockIdx.x * 256 + threadIdx.x;
    double z = (double)bg2[0];
    for (int c = 0; c < 192; c++)
        z += (double)Wg2[c] * G[(size_t)c * TS + s];
    double sig = 1.0 / (1.0 + exp(-z));

    __shared__ double red[256];
    red[threadIdx.x] = sig;
    __syncthreads();
    for (int off = 128; off > 0; off >>= 1) {
        if ((int)threadIdx.x < off) red[threadIdx.x] += red[threadIdx.x + off];
        __syncthreads();
    }
    if (threadIdx.x == 0) partial[blockIdx.x] = red[0];
}

__global__ void gate_final(const double* __restrict__ partial, int n,
                           int* __restrict__ dkp)
{
    double s = 0.0;
    for (int i = 0; i < n; i++) s += partial[i];
    double mean = s / (double)(8 * TS);
    int dk = (int)floor((double)CPH * mean);
    dk = dk < 1 ? 1 : (dk > CPH ? CPH : dk);
    *dkp = dk;
}

// ---------------------------------------------------------------------------
// Row L2 norm over spatial (fp32 in, fp64 accum). Writes 1/max(norm,1e-12).
// ---------------------------------------------------------------------------
__global__ __launch_bounds__(256)
void rownorm(const float* __restrict__ X, double* __restrict__ inv)
{
    const int r = blockIdx.x;
    const float* p = X + (size_t)r * TS;
    double ss = 0.0;
    for (int i = threadIdx.x; i < TS; i += 256) {
        double v = (double)p[i]; ss += v * v;
    }
    __shared__ double red[256];
    red[threadIdx.x] = ss;
    __syncthreads();
    for (int off = 128; off > 0; off >>= 1) {
        if ((int)threadIdx.x < off) red[threadIdx.x] += red[threadIdx.x + off];
        __syncthreads();
    }
    if (threadIdx.x == 0) inv[r] = 1.0 / fmax(sqrt(red[0]), 1e-12);
}

// ---------------------------------------------------------------------------
// S[b,h,c,d] = temp[h]*invq[c]*invk[d]*sum_s q[c,s] k[d,s]  (fp64 accum)
// ---------------------------------------------------------------------------
__global__ __launch_bounds__(256)
void qkt_s(const float* __restrict__ QD, const float* __restrict__ KD,
           const double* __restrict__ invq, const double* __restrict__ invk,
           const float* __restrict__ temperature, double* __restrict__ Sg)
{
    const int bh = blockIdx.x;
    const int b = bh >> 3, h = bh & 7;
    const int t = threadIdx.x;

    const float* qp = QD + ((size_t)b * CD + h * CPH) * TS;
    const float* kp = KD + ((size_t)b * CD + h * CPH) * TS;

    __shared__ float qs[CPH][129];
    __shared__ float ks[CPH][129];

    const int cb = (t >> 4) * 3;   // 0..45
    const int db = (t & 15) * 3;   // 0..45

    double acc[3][3] = {};

    for (int s0 = 0; s0 < TS; s0 += 128) {
        for (int idx = t; idx < CPH * 128; idx += 256) {
            const int r = idx >> 7, cc = idx & 127;
            qs[r][cc] = qp[(size_t)r * TS + s0 + cc];
            ks[r][cc] = kp[(size_t)r * TS + s0 + cc];
        }
        __syncthreads();
        #pragma unroll 2
        for (int ss = 0; ss < 128; ss++) {
            const double a0 = qs[cb + 0][ss], a1 = qs[cb + 1][ss], a2 = qs[cb + 2][ss];
            const double b0 = ks[db + 0][ss], b1 = ks[db + 1][ss], b2 = ks[db + 2][ss];
            acc[0][0] += a0 * b0; acc[0][1] += a0 * b1; acc[0][2] += a0 * b2;
            acc[1][0] += a1 * b0; acc[1][1] += a1 * b1; acc[1][2] += a1 * b2;
            acc[2][0] += a2 * b0; acc[2][1] += a2 * b1; acc[2][2] += a2 * b2;
        }
        __syncthreads();
    }

    const double tmp = (double)temperature[h];
    const int rowbase = b * CD + h * CPH;
    double* Sp = Sg + (size_t)bh * CPH * CPH;
    #pragma unroll
    for (int i = 0; i < 3; i++) {
        const double sq = invq[rowbase + cb + i] * tmp;
        #pragma unroll
        for (int j = 0; j < 3; j++)
            Sp[(cb + i) * CPH + db + j] = acc[i][j] * sq * invk[rowbase + db + j];
    }
}

// ---------------------------------------------------------------------------
// Per-row dynamic top-k threshold (counting rank == sort+slice incl. ties)
// + softmax in fp64; float P written to separate buffer Pf.
// ---------------------------------------------------------------------------
__global__ __launch_bounds__(64)
void topk_softmax(const double* __restrict__ Sg, const int* __restrict__ dkp,
                  float* __restrict__ Pf)
{
    const int bh = blockIdx.x;
    const int t = threadIdx.x;
    const double* Sp = Sg + (size_t)bh * CPH * CPH;

    __shared__ double p[CPH][CPH + 1];
    for (int idx = t; idx < CPH * CPH; idx += 64)
        p[idx / CPH][idx % CPH] = Sp[idx];
    __syncthreads();

    if (t < CPH) {
        const int dk = *dkp;
        const int r = t;
        double thr = 0.0;
        for (int o = 0; o < CPH; o++) {
            const double v = p[r][o];
            int g = 0, ge = 0;
            for (int u = 0; u < CPH; u++) {
                const double w = p[r][u];
                g  += (w > v);
                ge += (w >= v);
            }
            if (g < dk && dk <= ge) thr = v;
        }
        double m = -INFINITY;
        for (int o = 0; o < CPH; o++) {
            const double v = p[r][o];
            if (v >= thr && v > m) m = v;
        }
        double sum = 0.0;
        for (int o = 0; o < CPH; o++) {
            const double v = p[r][o];
            const double e = (v >= thr) ? exp(v - m) : 0.0;
            p[r][o] = e;
            sum += e;
        }
        const double is = 1.0 / sum;
        float* out = Pf + (size_t)bh * CPH * CPH;
        for (int o = 0; o < CPH; o++)
            out[r * CPH + o] = (float)(p[r][o] * is);
    }
}

// ---------------------------------------------------------------------------
// FP32 GEMM for 1x1 conv (full batch): O[b,m,s] = sum_k W[m,k] X[b,k,s]
// 128x128x16 tile, 256 thr, 8x8 micro. (v path + projection)
// ---------------------------------------------------------------------------
__global__ __launch_bounds__(256)
void gemm1x1(const float* __restrict__ X, const float* __restrict__ W,
             const float* __restrict__ bias, float* __restrict__ O,
             int K, int M, int S, int relu)
{
    const int b  = blockIdx.z;
    const int m0 = blockIdx.y * 128;
    const int n0 = blockIdx.x * 128;
    const float* Xb = X + (size_t)b * K * S;
    float* Ob = O + (size_t)b * M * S;

    const int t  = threadIdx.x;
    const int tm = t >> 4;
    const int tn = t & 15;

    __shared__ float As[16][132];
    __shared__ float Bs[16][132];

    float acc[8][8] = {};

    for (int k0 = 0; k0 < K; k0 += 16) {
        {
            const int m  = t >> 1;
            const int kk = (t & 1) * 8;
            const int row = m0 + m;
            float4 v0, v1;
            if (row < M) {
                const float* src = W + (size_t)row * K + k0 + kk;
                v0 = *(const float4*)(src);
                v1 = *(const float4*)(src + 4);
            } else {
                v0 = float4{0.f, 0.f, 0.f, 0.f};
                v1 = v0;
            }
            As[kk + 0][m] = v0.x; As[kk + 1][m] = v0.y;
            As[kk + 2][m] = v0.z; As[kk + 3][m] = v0.w;
            As[kk + 4][m] = v1.x; As[kk + 5][m] = v1.y;
            As[kk + 6][m] = v1.z; As[kk + 7][m] = v1.w;
        }
        {
            const int k = t >> 4;
            const int n = (t & 15) * 8;
            const float* src = Xb + (size_t)(k0 + k) * S + n0 + n;
            float4 v0 = *(const float4*)(src);
            float4 v1 = *(const float4*)(src + 4);
            *(float4*)&Bs[k][n]     = v0;
            *(float4*)&Bs[k][n + 4] = v1;
        }
        __syncthreads();

        #pragma unroll
        for (int k = 0; k < 16; k++) {
            float a[8], bb[8];
            *(float4*)&a[0]  = *(const float4*)&As[k][tm * 8];
            *(float4*)&a[4]  = *(const float4*)&As[k][tm * 8 + 4];
            *(float4*)&bb[0] = *(const float4*)&Bs[k][tn * 8];
            *(float4*)&bb[4] = *(const float4*)&Bs[k][tn * 8 + 4];
            #pragma unroll
            for (int i = 0; i < 8; i++)
                #pragma unroll
                for (int j = 0; j < 8; j++)
                    acc[i][j] += a[i] * bb[j];
        }
        __syncthreads();
    }

    #pragma unroll
    for (int i = 0; i < 8; i++) {
        const int m = m0 + tm * 8 + i;
        if (m >= M) break;
        const float bv = bias ? bias[m] : 0.f;
        float* dst = Ob + (size_t)m * S + n0 + tn * 8;
        float r[8];
        #pragma unroll
        for (int j = 0; j < 8; j++) {
            float v = acc[i][j] + bv;
            if (relu) v = fmaxf(v, 0.f);
            r[j] = v;
        }
        *(float4*)(dst)     = *(float4*)&r[0];
        *(float4*)(dst + 4) = *(float4*)&r[4];
    }
}

// ---------------------------------------------------------------------------
// FP32 depthwise 3x3 SAME (full batch), for the v path.
// ---------------------------------------------------------------------------
__global__ __launch_bounds__(256)
void dw3x3(const float* __restrict__ X, const float* __restrict__ Wd,
           float* __restrict__ O, int C)
{
    const int b = blockIdx.z, c = blockIdx.y;
    const int s = blockIdx.x * 256 + threadIdx.x;
    const int yy0 = s >> 6, xx0 = s & 63;
    const float* Xc = X + ((size_t)b * C + c) * TS;
    const float* w  = Wd + (size_t)c * 9;
    float acc = 0.f;
    #pragma unroll
    for (int dy = -1; dy <= 1; dy++) {
        const int yy = yy0 + dy;
        if (yy < 0 || yy > 63) continue;
        #pragma unroll
        for (int dx = -1; dx <= 1; dx++) {
            const int xx = xx0 + dx;
            if (xx < 0 || xx > 63) continue;
            acc += Xc[yy * 64 + xx] * w[(dy + 1) * 3 + (dx + 1)];
        }
    }
    O[((size_t)b * C + c) * TS + s] = acc;
}

// ---------------------------------------------------------------------------
// out[c,s] = sum_d P[c,d] * V[d,s].  grid (16 s-chunks, 64 bh), 256 threads.
// ---------------------------------------------------------------------------
__global__ __launch_bounds__(256)
void pv(const float* __restrict__ Pg, const float* __restrict__ VD,
        float* __restrict__ OAT)
{
    const int bh = blockIdx.y;
    const int b = bh >> 3, h = bh & 7;
    const int t = threadIdx.x;
    const int s = blockIdx.x * 256 + t;

    __shared__ float p[CPH][CPH + 1];
    const float* Sp = Pg + (size_t)bh * CPH * CPH;
    for (int idx = t; idx < CPH * CPH; idx += 256)
        p[idx / CPH][idx % CPH] = Sp[idx];
    __syncthreads();

    const float* vp = VD + ((size_t)b * CD + h * CPH) * TS;
    float* op = OAT + ((size_t)b * CD + h * CPH) * TS;

    float vv[CPH];
    #pragma unroll
    for (int d = 0; d < CPH; d++) vv[d] = vp[(size_t)d * TS + s];
    for (int c = 0; c < CPH; c++) {
        float o = 0.f;
        #pragma unroll
        for (int d = 0; d < CPH; d++) o += p[c][d] * vv[d];
        op[(size_t)c * TS + s] = o;
    }
}

// ---------------------------------------------------------------------------
extern "C" void kernel_launch(void* const* d_in, const int* in_sizes, int n_in,
                              void* d_out, int out_size, void* d_ws, size_t ws_size,
                              hipStream_t stream)
{
    const float* x     = (const float*)d_in[0];
    const float* y     = (const float*)d_in[1];
    const float* Wq    = (const float*)d_in[2];
    const float* Wqdw  = (const float*)d_in[3];
    const float* Wkv   = (const float*)d_in[4];
    const float* Wkvdw = (const float*)d_in[5];
    const float* Wproj = (const float*)d_in[6];
    const float* Wg1   = (const float*)d_in[7];
    const float* bg1   = (const float*)d_in[8];
    const float* Wg2   = (const float*)d_in[9];
    const float* bg2   = (const float*)d_in[10];
    const float* temp  = (const float*)d_in[11];
    float* out = (float*)d_out;

    // workspace: B1 (50MB: fp64 transients -> v1x1 -> attnout),
    //            B2 (50MB: qd fp32 -> P float), tail (~1.2MB)
    const size_t BIG   = (size_t)8 * CD * TS * 4;       // 50,331,648
    const size_t SG_B  = (size_t)64 * CPH * CPH * 8;    // 1,179,648
    const size_t INV_B = 3072 * 8;
    const size_t NEEDED = 2 * BIG + SG_B + 2 * INV_B + 1024 + 16;
    if (ws_size < NEEDED) return;

    char* w = (char*)d_ws;
    float*  B1   = (float*)(w);
    double* T0   = (double*)(w);                 // fp64 transient plane (12.6MB) in B1
    float*  qd   = (float*)(w + BIG);            // fp32 q (all batches) = B2
    float*  Pbuf = (float*)(w + BIG);            // float P, reuses B2 after qkt
    char* tail = w + 2 * BIG;
    double* Sg   = (double*)(tail);
    double* invq = (double*)(tail + SG_B);
    double* invk = (double*)(tail + SG_B + INV_B);
    double* part = (double*)(tail + SG_B + 2 * INV_B);
    int*    dkp  = (int*)(tail + SG_B + 2 * INV_B + 1024);

    float* kd = out;   // k (fp32, all batches) staged in d_out, dead before v lands

    const size_t planeF = (size_t)CD * TS;       // 1,572,864 floats per batch plane

    // ---- gate (fp64): g1 -> T0, partial sums, dk ----
    for (int b = 0; b < 8; b++) {
        gemm_f64<<<dim3(32, 3), 256, 0, stream>>>(x + b * planeF, Wg1, bg1, T0, CD, 192, TS, 1);
        gate2p_f64<<<16, 256, 0, stream>>>(T0, Wg2, bg2, part + b * 16);
    }
    gate_final<<<1, 1, 0, stream>>>(part, 128, dkp);

    // ---- q, k (fp64 GEMM + fp64 depthwise, rounded to fp32) ----
    for (int b = 0; b < 8; b++) {
        gemm_f64<<<dim3(32, 6), 256, 0, stream>>>(x + b * planeF, Wq, nullptr, T0, CD, CD, TS, 0);
        dwq_f64<<<dim3(16, CD), 256, 0, stream>>>(T0, Wqdw, qd + b * planeF);
        gemm_f64<<<dim3(32, 6), 256, 0, stream>>>(y + b * planeF, Wkv, nullptr, T0, CD, CD, TS, 0);
        dwq_f64<<<dim3(16, CD), 256, 0, stream>>>(T0, Wkvdw, kd + b * planeF);
    }

    // ---- norms + S ----
    rownorm<<<3072, 256, 0, stream>>>(qd, invq);
    rownorm<<<3072, 256, 0, stream>>>(kd, invk);
    qkt_s<<<64, 256, 0, stream>>>(qd, kd, invq, invk, temp, Sg);

    // ---- top-k + softmax -> float P (Pbuf overwrites qd region; qd dead) ----
    topk_softmax<<<64, 64, 0, stream>>>(Sg, dkp, Pbuf);

    // ---- v path (fp32): v1x1 -> B1, dw -> d_out (kd dead) ----
    gemm1x1<<<dim3(32, 3, 8), 256, 0, stream>>>(y, Wkv + (size_t)CD * CD, nullptr, B1, CD, CD, TS, 0);
    dw3x3<<<dim3(16, CD, 8), 256, 0, stream>>>(B1, Wkvdw + (size_t)CD * 9, out, CD);

    // ---- attn @ V -> B1 ----
    pv<<<dim3(16, 64), 256, 0, stream>>>(Pbuf, out, B1);

    // ---- projection -> d_out ----
    gemm1x1<<<dim3(32, 3, 8), 256, 0, stream>>>(B1, Wproj, nullptr, out, CD, CD, TS, 0);
}

// Round 5
// 1274.068 us; speedup vs baseline: 1.8561x; 1.8561x over previous
//
#include <hip/hip_runtime.h>
#include <cstddef>
#include <cstdint>
#include <cmath>

#define TS 4096   // spatial size H*W (64*64)
#define CD 384    // channels
#define NHEADS 8
#define CPH 48    // channels per head

// ---------------------------------------------------------------------------
// FP64-accumulating GEMM for 1x1 conv, batched over blockIdx.z:
// O[z][m,s] = sum_k W[m,k] X[z][k,s].  Tile 64(m)x128(n), K-step 16.
// ---------------------------------------------------------------------------
__global__ __launch_bounds__(256)
void gemm_f64(const float* __restrict__ X, size_t Xstride,
              const float* __restrict__ W, const float* __restrict__ bias,
              double* __restrict__ O, size_t Ostride,
              int K, int M, int S, int relu)
{
    const float* Xb = X + blockIdx.z * Xstride;
    double* Ob = O + blockIdx.z * Ostride;

    const int m0 = blockIdx.y * 64;
    const int n0 = blockIdx.x * 128;
    const int t  = threadIdx.x;

    __shared__ float As[16][68];
    __shared__ float Bs[16][136];

    const int tm = t >> 4;      // 0..15 -> m block of 4
    const int tn = t & 15;      // 0..15 -> n block of 8

    double acc[4][8] = {};

    for (int k0 = 0; k0 < K; k0 += 16) {
        {   // A: 64 m x 16 k ; thread -> m = t>>2, kq = (t&3)*4
            const int m = t >> 2, kq = (t & 3) * 4;
            const float4 v = *(const float4*)(W + (size_t)(m0 + m) * K + k0 + kq);
            As[kq + 0][m] = v.x; As[kq + 1][m] = v.y;
            As[kq + 2][m] = v.z; As[kq + 3][m] = v.w;
        }
        {   // B: 16 k x 128 n ; thread -> k = t>>4, n8 = (t&15)*8
            const int k = t >> 4, n8 = (t & 15) * 8;
            const float* src = Xb + (size_t)(k0 + k) * S + n0 + n8;
            float4 v0 = *(const float4*)(src);
            float4 v1 = *(const float4*)(src + 4);
            *(float4*)&Bs[k][n8]     = v0;
            *(float4*)&Bs[k][n8 + 4] = v1;
        }
        __syncthreads();

        #pragma unroll
        for (int k = 0; k < 16; k++) {
            const float4 a4  = *(const float4*)&As[k][tm * 4];
            const float4 b40 = *(const float4*)&Bs[k][tn * 8];
            const float4 b41 = *(const float4*)&Bs[k][tn * 8 + 4];
            const double a[4]  = {(double)a4.x, (double)a4.y, (double)a4.z, (double)a4.w};
            const double bb[8] = {(double)b40.x, (double)b40.y, (double)b40.z, (double)b40.w,
                                  (double)b41.x, (double)b41.y, (double)b41.z, (double)b41.w};
            #pragma unroll
            for (int i = 0; i < 4; i++)
                #pragma unroll
                for (int j = 0; j < 8; j++)
                    acc[i][j] += a[i] * bb[j];
        }
        __syncthreads();
    }

    #pragma unroll
    for (int i = 0; i < 4; i++) {
        const int m = m0 + tm * 4 + i;
        const double bv = bias ? (double)bias[m] : 0.0;
        double* dst = Ob + (size_t)m * S + n0 + tn * 8;
        #pragma unroll
        for (int j = 0; j < 8; j++) {
            double v = acc[i][j] + bv;
            if (relu && v < 0.0) v = 0.0;
            dst[j] = v;
        }
    }
}

// ---------------------------------------------------------------------------
// Depthwise 3x3 SAME on fp64 planes, batched over z; rounds result to fp32.
// grid (16, C, nbatch). Strides in elements.
// ---------------------------------------------------------------------------
__global__ __launch_bounds__(256)
void dwq_f64(const double* __restrict__ X, const float* __restrict__ Wd,
             float* __restrict__ O, int C)
{
    const int c = blockIdx.y;
    const int s = blockIdx.x * 256 + threadIdx.x;
    const int yy0 = s >> 6, xx0 = s & 63;
    const double* Xc = X + ((size_t)blockIdx.z * C + c) * TS;
    const float* w = Wd + (size_t)c * 9;
    double acc = 0.0;
    #pragma unroll
    for (int dy = -1; dy <= 1; dy++) {
        const int yy = yy0 + dy;
        if (yy < 0 || yy > 63) continue;
        #pragma unroll
        for (int dx = -1; dx <= 1; dx++) {
            const int xx = xx0 + dx;
            if (xx < 0 || xx > 63) continue;
            acc += Xc[yy * 64 + xx] * (double)w[(dy + 1) * 3 + (dx + 1)];
        }
    }
    O[((size_t)blockIdx.z * C + c) * TS + s] = (float)acc;
}

// ---------------------------------------------------------------------------
// Gate stage 2 on fp64 g1 planes [8][192][4096], batched over y.
// partial[y*16 + x] = deterministic block sum of sigmoid.
// ---------------------------------------------------------------------------
__global__ __launch_bounds__(256)
void gate2p_f64(const double* __restrict__ G0, const float* __restrict__ Wg2,
                const float* __restrict__ bg2, double* __restrict__ partial)
{
    const double* G = G0 + (size_t)blockIdx.y * 192 * TS;
    const int s = blockIdx.x * 256 + threadIdx.x;
    double z = (double)bg2[0];
    for (int c = 0; c < 192; c++)
        z += (double)Wg2[c] * G[(size_t)c * TS + s];
    double sig = 1.0 / (1.0 + exp(-z));

    __shared__ double red[256];
    red[threadIdx.x] = sig;
    __syncthreads();
    for (int off = 128; off > 0; off >>= 1) {
        if ((int)threadIdx.x < off) red[threadIdx.x] += red[threadIdx.x + off];
        __syncthreads();
    }
    if (threadIdx.x == 0) partial[blockIdx.y * 16 + blockIdx.x] = red[0];
}

__global__ void gate_final(const double* __restrict__ partial, int n,
                           int* __restrict__ dkp)
{
    double s = 0.0;
    for (int i = 0; i < n; i++) s += partial[i];
    double mean = s / (double)(8 * TS);
    int dk = (int)floor((double)CPH * mean);
    dk = dk < 1 ? 1 : (dk > CPH ? CPH : dk);
    *dkp = dk;
}

// ---------------------------------------------------------------------------
// Row L2 norm over spatial (fp32 in, fp64 accum). Writes 1/max(norm,1e-12).
// ---------------------------------------------------------------------------
__global__ __launch_bounds__(256)
void rownorm(const float* __restrict__ X, double* __restrict__ inv)
{
    const int r = blockIdx.x;
    const float* p = X + (size_t)r * TS;
    double ss = 0.0;
    for (int i = threadIdx.x; i < TS; i += 256) {
        double v = (double)p[i]; ss += v * v;
    }
    __shared__ double red[256];
    red[threadIdx.x] = ss;
    __syncthreads();
    for (int off = 128; off > 0; off >>= 1) {
        if ((int)threadIdx.x < off) red[threadIdx.x] += red[threadIdx.x + off];
        __syncthreads();
    }
    if (threadIdx.x == 0) inv[r] = 1.0 / fmax(sqrt(red[0]), 1e-12);
}

// ---------------------------------------------------------------------------
// QK^T partial sums: grid (16 spatial chunks, 64 bh). Each block computes the
// full 48x48 fp64 partial over its 256 spatial positions.
// Spart[ci][bh][c][d], no scaling (applied in reduce).
// ---------------------------------------------------------------------------
__global__ __launch_bounds__(256)
void qkt_part(const float* __restrict__ QD, const float* __restrict__ KD,
              double* __restrict__ Spart)
{
    const int ci = blockIdx.x;   // 0..15
    const int bh = blockIdx.y;   // 0..63
    const int b = bh >> 3, h = bh & 7;
    const int t = threadIdx.x;

    const float* qp = QD + ((size_t)b * CD + h * CPH) * TS + ci * 256;
    const float* kp = KD + ((size_t)b * CD + h * CPH) * TS + ci * 256;

    __shared__ float qs[CPH][132];
    __shared__ float ks[CPH][132];

    const int cb = (t >> 4) * 3;   // 0..45
    const int db = (t & 15) * 3;   // 0..45

    double acc[3][3] = {};

    #pragma unroll
    for (int sub = 0; sub < 2; sub++) {
        // 48 rows x 128 floats = 1536 float4s; 6 per thread
        for (int idx = t; idx < CPH * 32; idx += 256) {
            const int r = idx >> 5, c4 = (idx & 31) * 4;
            *(float4*)&qs[r][c4] = *(const float4*)(qp + (size_t)r * TS + sub * 128 + c4);
            *(float4*)&ks[r][c4] = *(const float4*)(kp + (size_t)r * TS + sub * 128 + c4);
        }
        __syncthreads();
        #pragma unroll 2
        for (int ss = 0; ss < 128; ss++) {
            const double a0 = qs[cb + 0][ss], a1 = qs[cb + 1][ss], a2 = qs[cb + 2][ss];
            const double b0 = ks[db + 0][ss], b1 = ks[db + 1][ss], b2 = ks[db + 2][ss];
            acc[0][0] += a0 * b0; acc[0][1] += a0 * b1; acc[0][2] += a0 * b2;
            acc[1][0] += a1 * b0; acc[1][1] += a1 * b1; acc[1][2] += a1 * b2;
            acc[2][0] += a2 * b0; acc[2][1] += a2 * b1; acc[2][2] += a2 * b2;
        }
        __syncthreads();
    }

    double* Sp = Spart + ((size_t)ci * 64 + bh) * (CPH * CPH);
    #pragma unroll
    for (int i = 0; i < 3; i++)
        #pragma unroll
        for (int j = 0; j < 3; j++)
            Sp[(cb + i) * CPH + db + j] = acc[i][j];
}

// ---------------------------------------------------------------------------
// Reduce partials in fixed chunk order, apply temp*invq*invk. grid 64.
// ---------------------------------------------------------------------------
__global__ __launch_bounds__(256)
void qkt_reduce(const double* __restrict__ Spart,
                const double* __restrict__ invq, const double* __restrict__ invk,
                const float* __restrict__ temperature, double* __restrict__ Sg)
{
    const int bh = blockIdx.x;
    const int b = bh >> 3, h = bh & 7;
    const int rowbase = b * CD + h * CPH;
    const double tmp = (double)temperature[h];
    for (int idx = threadIdx.x; idx < CPH * CPH; idx += 256) {
        const int c = idx / CPH, d = idx % CPH;
        double s = 0.0;
        for (int ci = 0; ci < 16; ci++)
            s += Spart[((size_t)ci * 64 + bh) * (CPH * CPH) + idx];
        Sg[(size_t)bh * CPH * CPH + idx] = s * invq[rowbase + c] * tmp * invk[rowbase + d];
    }
}

// ---------------------------------------------------------------------------
// Per-row dynamic top-k threshold (counting rank == sort+slice incl. ties)
// + softmax in fp64; float P written to Pf.
// ---------------------------------------------------------------------------
__global__ __launch_bounds__(64)
void topk_softmax(const double* __restrict__ Sg, const int* __restrict__ dkp,
                  float* __restrict__ Pf)
{
    const int bh = blockIdx.x;
    const int t = threadIdx.x;
    const double* Sp = Sg + (size_t)bh * CPH * CPH;

    __shared__ double p[CPH][CPH + 1];
    for (int idx = t; idx < CPH * CPH; idx += 64)
        p[idx / CPH][idx % CPH] = Sp[idx];
    __syncthreads();

    if (t < CPH) {
        const int dk = *dkp;
        const int r = t;
        double thr = 0.0;
        for (int o = 0; o < CPH; o++) {
            const double v = p[r][o];
            int g = 0, ge = 0;
            for (int u = 0; u < CPH; u++) {
                const double w = p[r][u];
                g  += (w > v);
                ge += (w >= v);
            }
            if (g < dk && dk <= ge) thr = v;
        }
        double m = -INFINITY;
        for (int o = 0; o < CPH; o++) {
            const double v = p[r][o];
            if (v >= thr && v > m) m = v;
        }
        double sum = 0.0;
        for (int o = 0; o < CPH; o++) {
            const double v = p[r][o];
            const double e = (v >= thr) ? exp(v - m) : 0.0;
            p[r][o] = e;
            sum += e;
        }
        const double is = 1.0 / sum;
        float* outp = Pf + (size_t)bh * CPH * CPH;
        for (int o = 0; o < CPH; o++)
            outp[r * CPH + o] = (float)(p[r][o] * is);
    }
}

// ---------------------------------------------------------------------------
// FP32 GEMM for 1x1 conv (full batch): O[b,m,s] = sum_k W[m,k] X[b,k,s]
// 128x128x16 tile, 256 thr, 8x8 micro. (v path + projection)
// ---------------------------------------------------------------------------
__global__ __launch_bounds__(256)
void gemm1x1(const float* __restrict__ X, const float* __restrict__ W,
             const float* __restrict__ bias, float* __restrict__ O,
             int K, int M, int S, int relu)
{
    const int b  = blockIdx.z;
    const int m0 = blockIdx.y * 128;
    const int n0 = blockIdx.x * 128;
    const float* Xb = X + (size_t)b * K * S;
    float* Ob = O + (size_t)b * M * S;

    const int t  = threadIdx.x;
    const int tm = t >> 4;
    const int tn = t & 15;

    __shared__ float As[16][132];
    __shared__ float Bs[16][132];

    float acc[8][8] = {};

    for (int k0 = 0; k0 < K; k0 += 16) {
        {
            const int m  = t >> 1;
            const int kk = (t & 1) * 8;
            const float* src = W + (size_t)(m0 + m) * K + k0 + kk;
            float4 v0 = *(const float4*)(src);
            float4 v1 = *(const float4*)(src + 4);
            As[kk + 0][m] = v0.x; As[kk + 1][m] = v0.y;
            As[kk + 2][m] = v0.z; As[kk + 3][m] = v0.w;
            As[kk + 4][m] = v1.x; As[kk + 5][m] = v1.y;
            As[kk + 6][m] = v1.z; As[kk + 7][m] = v1.w;
        }
        {
            const int k = t >> 4;
            const int n = (t & 15) * 8;
            const float* src = Xb + (size_t)(k0 + k) * S + n0 + n;
            float4 v0 = *(const float4*)(src);
            float4 v1 = *(const float4*)(src + 4);
            *(float4*)&Bs[k][n]     = v0;
            *(float4*)&Bs[k][n + 4] = v1;
        }
        __syncthreads();

        #pragma unroll
        for (int k = 0; k < 16; k++) {
            float a[8], bb[8];
            *(float4*)&a[0]  = *(const float4*)&As[k][tm * 8];
            *(float4*)&a[4]  = *(const float4*)&As[k][tm * 8 + 4];
            *(float4*)&bb[0] = *(const float4*)&Bs[k][tn * 8];
            *(float4*)&bb[4] = *(const float4*)&Bs[k][tn * 8 + 4];
            #pragma unroll
            for (int i = 0; i < 8; i++)
                #pragma unroll
                for (int j = 0; j < 8; j++)
                    acc[i][j] += a[i] * bb[j];
        }
        __syncthreads();
    }

    #pragma unroll
    for (int i = 0; i < 8; i++) {
        const int m = m0 + tm * 8 + i;
        const float bv = bias ? bias[m] : 0.f;
        float* dst = Ob + (size_t)m * S + n0 + tn * 8;
        float r[8];
        #pragma unroll
        for (int j = 0; j < 8; j++) {
            float v = acc[i][j] + bv;
            if (relu) v = fmaxf(v, 0.f);
            r[j] = v;
        }
        *(float4*)(dst)     = *(float4*)&r[0];
        *(float4*)(dst + 4) = *(float4*)&r[4];
    }
}

// ---------------------------------------------------------------------------
// FP32 depthwise 3x3 SAME (full batch), for the v path.
// ---------------------------------------------------------------------------
__global__ __launch_bounds__(256)
void dw3x3(const float* __restrict__ X, const float* __restrict__ Wd,
           float* __restrict__ O, int C)
{
    const int b = blockIdx.z, c = blockIdx.y;
    const int s = blockIdx.x * 256 + threadIdx.x;
    const int yy0 = s >> 6, xx0 = s & 63;
    const float* Xc = X + ((size_t)b * C + c) * TS;
    const float* w  = Wd + (size_t)c * 9;
    float acc = 0.f;
    #pragma unroll
    for (int dy = -1; dy <= 1; dy++) {
        const int yy = yy0 + dy;
        if (yy < 0 || yy > 63) continue;
        #pragma unroll
        for (int dx = -1; dx <= 1; dx++) {
            const int xx = xx0 + dx;
            if (xx < 0 || xx > 63) continue;
            acc += Xc[yy * 64 + xx] * w[(dy + 1) * 3 + (dx + 1)];
        }
    }
    O[((size_t)b * C + c) * TS + s] = acc;
}

// ---------------------------------------------------------------------------
// out[c,s] = sum_d P[c,d] * V[d,s].  grid (16 s-chunks, 64 bh), 256 threads.
// ---------------------------------------------------------------------------
__global__ __launch_bounds__(256)
void pv(const float* __restrict__ Pg, const float* __restrict__ VD,
        float* __restrict__ OAT)
{
    const int bh = blockIdx.y;
    const int b = bh >> 3, h = bh & 7;
    const int t = threadIdx.x;
    const int s = blockIdx.x * 256 + t;

    __shared__ float p[CPH][CPH + 1];
    const float* Sp = Pg + (size_t)bh * CPH * CPH;
    for (int idx = t; idx < CPH * CPH; idx += 256)
        p[idx / CPH][idx % CPH] = Sp[idx];
    __syncthreads();

    const float* vp = VD + ((size_t)b * CD + h * CPH) * TS;
    float* op = OAT + ((size_t)b * CD + h * CPH) * TS;

    float vv[CPH];
    #pragma unroll
    for (int d = 0; d < CPH; d++) vv[d] = vp[(size_t)d * TS + s];
    for (int c = 0; c < CPH; c++) {
        float o = 0.f;
        #pragma unroll
        for (int d = 0; d < CPH; d++) o += p[c][d] * vv[d];
        op[(size_t)c * TS + s] = o;
    }
}

// ---------------------------------------------------------------------------
extern "C" void kernel_launch(void* const* d_in, const int* in_sizes, int n_in,
                              void* d_out, int out_size, void* d_ws, size_t ws_size,
                              hipStream_t stream)
{
    const float* x     = (const float*)d_in[0];
    const float* y     = (const float*)d_in[1];
    const float* Wq    = (const float*)d_in[2];
    const float* Wqdw  = (const float*)d_in[3];
    const float* Wkv   = (const float*)d_in[4];
    const float* Wkvdw = (const float*)d_in[5];
    const float* Wproj = (const float*)d_in[6];
    const float* Wg1   = (const float*)d_in[7];
    const float* bg1   = (const float*)d_in[8];
    const float* Wg2   = (const float*)d_in[9];
    const float* bg2   = (const float*)d_in[10];
    const float* temp  = (const float*)d_in[11];
    float* out = (float*)d_out;

    // workspace: B1 (50MB: fp64 transients / QK^T partials / v1x1 / attnout),
    //            B2 (50MB: qd fp32 -> P float), tail (~1.2MB)
    const size_t BIG   = (size_t)8 * CD * TS * 4;       // 50,331,648
    const size_t SG_B  = (size_t)64 * CPH * CPH * 8;    // 1,179,648
    const size_t INV_B = 3072 * 8;
    const size_t NEEDED = 2 * BIG + SG_B + 2 * INV_B + 1024 + 16;
    if (ws_size < NEEDED) return;

    char* w = (char*)d_ws;
    float*  B1    = (float*)(w);
    double* T0    = (double*)(w);                // fp64 transient planes in B1
    double* Spart = (double*)(w);                // QK^T partials (18.9MB) in B1
    float*  qd    = (float*)(w + BIG);           // fp32 q (all batches) = B2
    float*  Pbuf  = (float*)(w + BIG);           // float P, reuses B2 after qkt
    char* tail = w + 2 * BIG;
    double* Sg   = (double*)(tail);
    double* invq = (double*)(tail + SG_B);
    double* invk = (double*)(tail + SG_B + INV_B);
    double* part = (double*)(tail + SG_B + 2 * INV_B);
    int*    dkp  = (int*)(tail + SG_B + 2 * INV_B + 1024);

    float* kd = out;   // k (fp32, all batches) staged in d_out, dead before v lands

    const size_t planeF = (size_t)CD * TS;       // fp32 elements per batch plane

    // ---- gate (fp64, batched): g1 -> T0 (8x192 planes = BIG), dk ----
    gemm_f64<<<dim3(32, 3, 8), 256, 0, stream>>>(x, planeF, Wg1, bg1,
                                                 T0, (size_t)192 * TS, CD, 192, TS, 1);
    gate2p_f64<<<dim3(16, 8), 256, 0, stream>>>(T0, Wg2, bg2, part);
    gate_final<<<1, 1, 0, stream>>>(part, 128, dkp);

    // ---- q (fp64 GEMM + fp64 dw -> fp32), two groups of 4 batches ----
    for (int g = 0; g < 2; g++) {
        const size_t off = (size_t)g * 4 * planeF;
        gemm_f64<<<dim3(32, 6, 4), 256, 0, stream>>>(x + off, planeF, Wq, nullptr,
                                                     T0, (size_t)CD * TS, CD, CD, TS, 0);
        dwq_f64<<<dim3(16, CD, 4), 256, 0, stream>>>(T0, Wqdw, qd + off, CD);
    }
    // ---- k ----
    for (int g = 0; g < 2; g++) {
        const size_t off = (size_t)g * 4 * planeF;
        gemm_f64<<<dim3(32, 6, 4), 256, 0, stream>>>(y + off, planeF, Wkv, nullptr,
                                                     T0, (size_t)CD * TS, CD, CD, TS, 0);
        dwq_f64<<<dim3(16, CD, 4), 256, 0, stream>>>(T0, Wkvdw, kd + off, CD);
    }

    // ---- norms + S (split over 16 spatial chunks; partials in B1, T0 dead) ----
    rownorm<<<3072, 256, 0, stream>>>(qd, invq);
    rownorm<<<3072, 256, 0, stream>>>(kd, invk);
    qkt_part<<<dim3(16, 64), 256, 0, stream>>>(qd, kd, Spart);
    qkt_reduce<<<64, 256, 0, stream>>>(Spart, invq, invk, temp, Sg);

    // ---- top-k + softmax -> float P (Pbuf overwrites qd region; qd dead) ----
    topk_softmax<<<64, 64, 0, stream>>>(Sg, dkp, Pbuf);

    // ---- v path (fp32): v1x1 -> B1 (Spart dead), dw -> d_out (kd dead) ----
    gemm1x1<<<dim3(32, 3, 8), 256, 0, stream>>>(y, Wkv + (size_t)CD * CD, nullptr, B1, CD, CD, TS, 0);
    dw3x3<<<dim3(16, CD, 8), 256, 0, stream>>>(B1, Wkvdw + (size_t)CD * 9, out, CD);

    // ---- attn @ V -> B1 ----
    pv<<<dim3(16, 64), 256, 0, stream>>>(Pbuf, out, B1);

    // ---- projection -> d_out ----
    gemm1x1<<<dim3(32, 3, 8), 256, 0, stream>>>(B1, Wproj, nullptr, out, CD, CD, TS, 0);
}

// Round 6
// 1166.085 us; speedup vs baseline: 2.0279x; 1.0926x over previous
//
#include <hip/hip_runtime.h>
#include <cstddef>
#include <cstdint>
#include <cmath>

#define TS 4096   // spatial size H*W (64*64)
#define CD 384    // channels
#define NHEADS 8
#define CPH 48    // channels per head

// ---------------------------------------------------------------------------
// FP64-accumulating GEMM for 1x1 conv, fp32 output, batched over blockIdx.z:
// O[z][m,s] = (float)( sum_k W[m,k] X[z][k,s] )  Tile 64(m)x128(n), K-step 16.
// ---------------------------------------------------------------------------
__global__ __launch_bounds__(256)
void gemm_f64f(const float* __restrict__ X, size_t Xstride,
               const float* __restrict__ W, const float* __restrict__ bias,
               float* __restrict__ O, size_t Ostride,
               int K, int M, int S, int relu)
{
    const float* Xb = X + blockIdx.z * Xstride;
    float* Ob = O + blockIdx.z * Ostride;

    const int m0 = blockIdx.y * 64;
    const int n0 = blockIdx.x * 128;
    const int t  = threadIdx.x;

    __shared__ float As[16][68];
    __shared__ float Bs[16][136];

    const int tm = t >> 4;      // 0..15 -> m block of 4
    const int tn = t & 15;      // 0..15 -> n block of 8

    double acc[4][8] = {};

    for (int k0 = 0; k0 < K; k0 += 16) {
        {   // A: 64 m x 16 k ; thread -> m = t>>2, kq = (t&3)*4
            const int m = t >> 2, kq = (t & 3) * 4;
            const float4 v = *(const float4*)(W + (size_t)(m0 + m) * K + k0 + kq);
            As[kq + 0][m] = v.x; As[kq + 1][m] = v.y;
            As[kq + 2][m] = v.z; As[kq + 3][m] = v.w;
        }
        {   // B: 16 k x 128 n ; thread -> k = t>>4, n8 = (t&15)*8
            const int k = t >> 4, n8 = (t & 15) * 8;
            const float* src = Xb + (size_t)(k0 + k) * S + n0 + n8;
            float4 v0 = *(const float4*)(src);
            float4 v1 = *(const float4*)(src + 4);
            *(float4*)&Bs[k][n8]     = v0;
            *(float4*)&Bs[k][n8 + 4] = v1;
        }
        __syncthreads();

        #pragma unroll
        for (int k = 0; k < 16; k++) {
            const float4 a4  = *(const float4*)&As[k][tm * 4];
            const float4 b40 = *(const float4*)&Bs[k][tn * 8];
            const float4 b41 = *(const float4*)&Bs[k][tn * 8 + 4];
            const double a[4]  = {(double)a4.x, (double)a4.y, (double)a4.z, (double)a4.w};
            const double bb[8] = {(double)b40.x, (double)b40.y, (double)b40.z, (double)b40.w,
                                  (double)b41.x, (double)b41.y, (double)b41.z, (double)b41.w};
            #pragma unroll
            for (int i = 0; i < 4; i++)
                #pragma unroll
                for (int j = 0; j < 8; j++)
                    acc[i][j] += a[i] * bb[j];
        }
        __syncthreads();
    }

    #pragma unroll
    for (int i = 0; i < 4; i++) {
        const int m = m0 + tm * 4 + i;
        const double bv = bias ? (double)bias[m] : 0.0;
        float* dst = Ob + (size_t)m * S + n0 + tn * 8;
        float r[8];
        #pragma unroll
        for (int j = 0; j < 8; j++) {
            double v = acc[i][j] + bv;
            if (relu && v < 0.0) v = 0.0;
            r[j] = (float)v;
        }
        *(float4*)(dst)     = *(float4*)&r[0];
        *(float4*)(dst + 4) = *(float4*)&r[4];
    }
}

// ---------------------------------------------------------------------------
// FP32 depthwise 3x3 SAME, batched over z. grid (16, C, nbatch).
// ---------------------------------------------------------------------------
__global__ __launch_bounds__(256)
void dw3x3(const float* __restrict__ X, const float* __restrict__ Wd,
           float* __restrict__ O, int C)
{
    const int b = blockIdx.z, c = blockIdx.y;
    const int s = blockIdx.x * 256 + threadIdx.x;
    const int yy0 = s >> 6, xx0 = s & 63;
    const float* Xc = X + ((size_t)b * C + c) * TS;
    const float* w  = Wd + (size_t)c * 9;
    float acc = 0.f;
    #pragma unroll
    for (int dy = -1; dy <= 1; dy++) {
        const int yy = yy0 + dy;
        if (yy < 0 || yy > 63) continue;
        #pragma unroll
        for (int dx = -1; dx <= 1; dx++) {
            const int xx = xx0 + dx;
            if (xx < 0 || xx > 63) continue;
            acc += Xc[yy * 64 + xx] * w[(dy + 1) * 3 + (dx + 1)];
        }
    }
    O[((size_t)b * C + c) * TS + s] = acc;
}

// ---------------------------------------------------------------------------
// Gate stage 2 on fp32 g1 planes [8][192][4096], fp64 dot + sigmoid,
// deterministic block sums. grid (16, 8).
// ---------------------------------------------------------------------------
__global__ __launch_bounds__(256)
void gate2p(const float* __restrict__ G0, const float* __restrict__ Wg2,
            const float* __restrict__ bg2, double* __restrict__ partial)
{
    const float* G = G0 + (size_t)blockIdx.y * 192 * TS;
    const int s = blockIdx.x * 256 + threadIdx.x;
    double z = (double)bg2[0];
    for (int c = 0; c < 192; c++)
        z += (double)Wg2[c] * (double)G[(size_t)c * TS + s];
    double sig = 1.0 / (1.0 + exp(-z));

    __shared__ double red[256];
    red[threadIdx.x] = sig;
    __syncthreads();
    for (int off = 128; off > 0; off >>= 1) {
        if ((int)threadIdx.x < off) red[threadIdx.x] += red[threadIdx.x + off];
        __syncthreads();
    }
    if (threadIdx.x == 0) partial[blockIdx.y * 16 + blockIdx.x] = red[0];
}

__global__ void gate_final(const double* __restrict__ partial, int n,
                           int* __restrict__ dkp)
{
    double s = 0.0;
    for (int i = 0; i < n; i++) s += partial[i];
    double mean = s / (double)(8 * TS);
    int dk = (int)floor((double)CPH * mean);
    dk = dk < 1 ? 1 : (dk > CPH ? CPH : dk);
    *dkp = dk;
}

// ---------------------------------------------------------------------------
// Row L2 norm over spatial (fp32 in, fp64 accum). Writes 1/max(norm,1e-12).
// ---------------------------------------------------------------------------
__global__ __launch_bounds__(256)
void rownorm(const float* __restrict__ X, double* __restrict__ inv)
{
    const int r = blockIdx.x;
    const float* p = X + (size_t)r * TS;
    double ss = 0.0;
    for (int i = threadIdx.x; i < TS; i += 256) {
        double v = (double)p[i]; ss += v * v;
    }
    __shared__ double red[256];
    red[threadIdx.x] = ss;
    __syncthreads();
    for (int off = 128; off > 0; off >>= 1) {
        if ((int)threadIdx.x < off) red[threadIdx.x] += red[threadIdx.x + off];
        __syncthreads();
    }
    if (threadIdx.x == 0) inv[r] = 1.0 / fmax(sqrt(red[0]), 1e-12);
}

// ---------------------------------------------------------------------------
// QK^T partial sums: grid (16 spatial chunks, 64 bh). fp64 partial 48x48.
// ---------------------------------------------------------------------------
__global__ __launch_bounds__(256)
void qkt_part(const float* __restrict__ QD, const float* __restrict__ KD,
              double* __restrict__ Spart)
{
    const int ci = blockIdx.x;   // 0..15
    const int bh = blockIdx.y;   // 0..63
    const int b = bh >> 3, h = bh & 7;
    const int t = threadIdx.x;

    const float* qp = QD + ((size_t)b * CD + h * CPH) * TS + ci * 256;
    const float* kp = KD + ((size_t)b * CD + h * CPH) * TS + ci * 256;

    __shared__ float qs[CPH][132];
    __shared__ float ks[CPH][132];

    const int cb = (t >> 4) * 3;   // 0..45
    const int db = (t & 15) * 3;   // 0..45

    double acc[3][3] = {};

    #pragma unroll
    for (int sub = 0; sub < 2; sub++) {
        for (int idx = t; idx < CPH * 32; idx += 256) {
            const int r = idx >> 5, c4 = (idx & 31) * 4;
            *(float4*)&qs[r][c4] = *(const float4*)(qp + (size_t)r * TS + sub * 128 + c4);
            *(float4*)&ks[r][c4] = *(const float4*)(kp + (size_t)r * TS + sub * 128 + c4);
        }
        __syncthreads();
        #pragma unroll 2
        for (int ss = 0; ss < 128; ss++) {
            const double a0 = qs[cb + 0][ss], a1 = qs[cb + 1][ss], a2 = qs[cb + 2][ss];
            const double b0 = ks[db + 0][ss], b1 = ks[db + 1][ss], b2 = ks[db + 2][ss];
            acc[0][0] += a0 * b0; acc[0][1] += a0 * b1; acc[0][2] += a0 * b2;
            acc[1][0] += a1 * b0; acc[1][1] += a1 * b1; acc[1][2] += a1 * b2;
            acc[2][0] += a2 * b0; acc[2][1] += a2 * b1; acc[2][2] += a2 * b2;
        }
        __syncthreads();
    }

    double* Sp = Spart + ((size_t)ci * 64 + bh) * (CPH * CPH);
    #pragma unroll
    for (int i = 0; i < 3; i++)
        #pragma unroll
        for (int j = 0; j < 3; j++)
            Sp[(cb + i) * CPH + db + j] = acc[i][j];
}

// ---------------------------------------------------------------------------
// Reduce partials in fixed chunk order, apply temp*invq*invk. grid 64.
// ---------------------------------------------------------------------------
__global__ __launch_bounds__(256)
void qkt_reduce(const double* __restrict__ Spart,
                const double* __restrict__ invq, const double* __restrict__ invk,
                const float* __restrict__ temperature, double* __restrict__ Sg)
{
    const int bh = blockIdx.x;
    const int b = bh >> 3, h = bh & 7;
    const int rowbase = b * CD + h * CPH;
    const double tmp = (double)temperature[h];
    for (int idx = threadIdx.x; idx < CPH * CPH; idx += 256) {
        const int c = idx / CPH, d = idx % CPH;
        double s = 0.0;
        for (int ci = 0; ci < 16; ci++)
            s += Spart[((size_t)ci * 64 + bh) * (CPH * CPH) + idx];
        Sg[(size_t)bh * CPH * CPH + idx] = s * invq[rowbase + c] * tmp * invk[rowbase + d];
    }
}

// ---------------------------------------------------------------------------
// Per-row dynamic top-k threshold (counting rank == sort+slice incl. ties)
// + softmax in fp64; float P written to Pf.
// ---------------------------------------------------------------------------
__global__ __launch_bounds__(64)
void topk_softmax(const double* __restrict__ Sg, const int* __restrict__ dkp,
                  float* __restrict__ Pf)
{
    const int bh = blockIdx.x;
    const int t = threadIdx.x;
    const double* Sp = Sg + (size_t)bh * CPH * CPH;

    __shared__ double p[CPH][CPH + 1];
    for (int idx = t; idx < CPH * CPH; idx += 64)
        p[idx / CPH][idx % CPH] = Sp[idx];
    __syncthreads();

    if (t < CPH) {
        const int dk = *dkp;
        const int r = t;
        double thr = 0.0;
        for (int o = 0; o < CPH; o++) {
            const double v = p[r][o];
            int g = 0, ge = 0;
            for (int u = 0; u < CPH; u++) {
                const double w = p[r][u];
                g  += (w > v);
                ge += (w >= v);
            }
            if (g < dk && dk <= ge) thr = v;
        }
        double m = -INFINITY;
        for (int o = 0; o < CPH; o++) {
            const double v = p[r][o];
            if (v >= thr && v > m) m = v;
        }
        double sum = 0.0;
        for (int o = 0; o < CPH; o++) {
            const double v = p[r][o];
            const double e = (v >= thr) ? exp(v - m) : 0.0;
            p[r][o] = e;
            sum += e;
        }
        const double is = 1.0 / sum;
        float* outp = Pf + (size_t)bh * CPH * CPH;
        for (int o = 0; o < CPH; o++)
            outp[r * CPH + o] = (float)(p[r][o] * is);
    }
}

// ---------------------------------------------------------------------------
// FP32 GEMM for 1x1 conv (full batch): O[b,m,s] = sum_k W[m,k] X[b,k,s]
// 128x128x16 tile, 256 thr, 8x8 micro. (v path + projection)
// ---------------------------------------------------------------------------
__global__ __launch_bounds__(256)
void gemm1x1(const float* __restrict__ X, const float* __restrict__ W,
             const float* __restrict__ bias, float* __restrict__ O,
             int K, int M, int S, int relu)
{
    const int b  = blockIdx.z;
    const int m0 = blockIdx.y * 128;
    const int n0 = blockIdx.x * 128;
    const float* Xb = X + (size_t)b * K * S;
    float* Ob = O + (size_t)b * M * S;

    const int t  = threadIdx.x;
    const int tm = t >> 4;
    const int tn = t & 15;

    __shared__ float As[16][132];
    __shared__ float Bs[16][132];

    float acc[8][8] = {};

    for (int k0 = 0; k0 < K; k0 += 16) {
        {
            const int m  = t >> 1;
            const int kk = (t & 1) * 8;
            const float* src = W + (size_t)(m0 + m) * K + k0 + kk;
            float4 v0 = *(const float4*)(src);
            float4 v1 = *(const float4*)(src + 4);
            As[kk + 0][m] = v0.x; As[kk + 1][m] = v0.y;
            As[kk + 2][m] = v0.z; As[kk + 3][m] = v0.w;
            As[kk + 4][m] = v1.x; As[kk + 5][m] = v1.y;
            As[kk + 6][m] = v1.z; As[kk + 7][m] = v1.w;
        }
        {
            const int k = t >> 4;
            const int n = (t & 15) * 8;
            const float* src = Xb + (size_t)(k0 + k) * S + n0 + n;
            float4 v0 = *(const float4*)(src);
            float4 v1 = *(const float4*)(src + 4);
            *(float4*)&Bs[k][n]     = v0;
            *(float4*)&Bs[k][n + 4] = v1;
        }
        __syncthreads();

        #pragma unroll
        for (int k = 0; k < 16; k++) {
            float a[8], bb[8];
            *(float4*)&a[0]  = *(const float4*)&As[k][tm * 8];
            *(float4*)&a[4]  = *(const float4*)&As[k][tm * 8 + 4];
            *(float4*)&bb[0] = *(const float4*)&Bs[k][tn * 8];
            *(float4*)&bb[4] = *(const float4*)&Bs[k][tn * 8 + 4];
            #pragma unroll
            for (int i = 0; i < 8; i++)
                #pragma unroll
                for (int j = 0; j < 8; j++)
                    acc[i][j] += a[i] * bb[j];
        }
        __syncthreads();
    }

    #pragma unroll
    for (int i = 0; i < 8; i++) {
        const int m = m0 + tm * 8 + i;
        const float bv = bias ? bias[m] : 0.f;
        float* dst = Ob + (size_t)m * S + n0 + tn * 8;
        float r[8];
        #pragma unroll
        for (int j = 0; j < 8; j++) {
            float v = acc[i][j] + bv;
            if (relu) v = fmaxf(v, 0.f);
            r[j] = v;
        }
        *(float4*)(dst)     = *(float4*)&r[0];
        *(float4*)(dst + 4) = *(float4*)&r[4];
    }
}

// ---------------------------------------------------------------------------
// out[c,s] = sum_d P[c,d] * V[d,s].  grid (16 s-chunks, 64 bh), 256 threads.
// ---------------------------------------------------------------------------
__global__ __launch_bounds__(256)
void pv(const float* __restrict__ Pg, const float* __restrict__ VD,
        float* __restrict__ OAT)
{
    const int bh = blockIdx.y;
    const int b = bh >> 3, h = bh & 7;
    const int t = threadIdx.x;
    const int s = blockIdx.x * 256 + t;

    __shared__ float p[CPH][CPH + 1];
    const float* Sp = Pg + (size_t)bh * CPH * CPH;
    for (int idx = t; idx < CPH * CPH; idx += 256)
        p[idx / CPH][idx % CPH] = Sp[idx];
    __syncthreads();

    const float* vp = VD + ((size_t)b * CD + h * CPH) * TS;
    float* op = OAT + ((size_t)b * CD + h * CPH) * TS;

    float vv[CPH];
    #pragma unroll
    for (int d = 0; d < CPH; d++) vv[d] = vp[(size_t)d * TS + s];
    for (int c = 0; c < CPH; c++) {
        float o = 0.f;
        #pragma unroll
        for (int d = 0; d < CPH; d++) o += p[c][d] * vv[d];
        op[(size_t)c * TS + s] = o;
    }
}

// ---------------------------------------------------------------------------
extern "C" void kernel_launch(void* const* d_in, const int* in_sizes, int n_in,
                              void* d_out, int out_size, void* d_ws, size_t ws_size,
                              hipStream_t stream)
{
    const float* x     = (const float*)d_in[0];
    const float* y     = (const float*)d_in[1];
    const float* Wq    = (const float*)d_in[2];
    const float* Wqdw  = (const float*)d_in[3];
    const float* Wkv   = (const float*)d_in[4];
    const float* Wkvdw = (const float*)d_in[5];
    const float* Wproj = (const float*)d_in[6];
    const float* Wg1   = (const float*)d_in[7];
    const float* bg1   = (const float*)d_in[8];
    const float* Wg2   = (const float*)d_in[9];
    const float* bg2   = (const float*)d_in[10];
    const float* temp  = (const float*)d_in[11];
    float* out = (float*)d_out;

    // workspace: B1 (50MB: g1 / q1x1 / k1x1 / Spart / v1x1 / attnout),
    //            B2 (50MB: qd -> P), tail (~1.2MB)
    const size_t BIG   = (size_t)8 * CD * TS * 4;       // 50,331,648
    const size_t SG_B  = (size_t)64 * CPH * CPH * 8;    // 1,179,648
    const size_t INV_B = 3072 * 8;
    const size_t NEEDED = 2 * BIG + SG_B + 2 * INV_B + 1024 + 16;
    if (ws_size < NEEDED) return;

    char* w = (char*)d_ws;
    float*  B1    = (float*)(w);
    double* Spart = (double*)(w);                // QK^T partials (18.9MB) in B1
    float*  qd    = (float*)(w + BIG);           // fp32 q (all batches) = B2
    float*  Pbuf  = (float*)(w + BIG);           // float P, reuses B2 after qkt
    char* tail = w + 2 * BIG;
    double* Sg   = (double*)(tail);
    double* invq = (double*)(tail + SG_B);
    double* invk = (double*)(tail + SG_B + INV_B);
    double* part = (double*)(tail + SG_B + 2 * INV_B);
    int*    dkp  = (int*)(tail + SG_B + 2 * INV_B + 1024);

    float* kd = out;   // k (fp32, all batches) staged in d_out, dead before v lands

    const size_t planeF = (size_t)CD * TS;       // fp32 elements per batch plane

    // ---- gate: g1 (fp64 accum -> fp32 planes in B1), z-dot fp64, dk ----
    gemm_f64f<<<dim3(32, 3, 8), 256, 0, stream>>>(x, planeF, Wg1, bg1,
                                                  B1, (size_t)192 * TS, CD, 192, TS, 1);
    gate2p<<<dim3(16, 8), 256, 0, stream>>>(B1, Wg2, bg2, part);
    gate_final<<<1, 1, 0, stream>>>(part, 128, dkp);

    // ---- q: 1x1 (fp64 accum -> fp32 B1, all 8 batches), dw -> qd ----
    gemm_f64f<<<dim3(32, 6, 8), 256, 0, stream>>>(x, planeF, Wq, nullptr,
                                                  B1, planeF, CD, CD, TS, 0);
    dw3x3<<<dim3(16, CD, 8), 256, 0, stream>>>(B1, Wqdw, qd, CD);

    // ---- k: 1x1 -> B1, dw -> kd (d_out scratch) ----
    gemm_f64f<<<dim3(32, 6, 8), 256, 0, stream>>>(y, planeF, Wkv, nullptr,
                                                  B1, planeF, CD, CD, TS, 0);
    dw3x3<<<dim3(16, CD, 8), 256, 0, stream>>>(B1, Wkvdw, kd, CD);

    // ---- norms + S (partials in B1; k-1x1 output dead after dw) ----
    rownorm<<<3072, 256, 0, stream>>>(qd, invq);
    rownorm<<<3072, 256, 0, stream>>>(kd, invk);
    qkt_part<<<dim3(16, 64), 256, 0, stream>>>(qd, kd, Spart);
    qkt_reduce<<<64, 256, 0, stream>>>(Spart, invq, invk, temp, Sg);

    // ---- top-k + softmax -> float P (overwrites qd; qd dead) ----
    topk_softmax<<<64, 64, 0, stream>>>(Sg, dkp, Pbuf);

    // ---- v path (fp32): v1x1 -> B1 (Spart dead), dw -> d_out (kd dead) ----
    gemm1x1<<<dim3(32, 3, 8), 256, 0, stream>>>(y, Wkv + (size_t)CD * CD, nullptr, B1, CD, CD, TS, 0);
    dw3x3<<<dim3(16, CD, 8), 256, 0, stream>>>(B1, Wkvdw + (size_t)CD * 9, out, CD);

    // ---- attn @ V -> B1 ----
    pv<<<dim3(16, 64), 256, 0, stream>>>(Pbuf, out, B1);

    // ---- projection -> d_out ----
    gemm1x1<<<dim3(32, 3, 8), 256, 0, stream>>>(B1, Wproj, nullptr, out, CD, CD, TS, 0);
}

// Round 7
// 1108.730 us; speedup vs baseline: 2.1328x; 1.0517x over previous
//
#include <hip/hip_runtime.h>
#include <cstddef>
#include <cstdint>
#include <cmath>

#define TS 4096   // spatial size H*W (64*64)
#define CD 384    // channels
#define NHEADS 8
#define CPH 48    // channels per head

// ---------------------------------------------------------------------------
// FP32 GEMM for 1x1 conv (full batch): O[b,m,s] = sum_k W[m,k] X[b,k,s]
// 128x128x16 tile, 256 thr, 8x8 micro. Conflict-free B reads (tn*4 / 64+tn*4).
// Handles M not multiple of 128 (gate M=192).
// ---------------------------------------------------------------------------
__global__ __launch_bounds__(256)
void gemm1x1(const float* __restrict__ X, const float* __restrict__ W,
             const float* __restrict__ bias, float* __restrict__ O,
             int K, int M, int S, int relu)
{
    const int b  = blockIdx.z;
    const int m0 = blockIdx.y * 128;
    const int n0 = blockIdx.x * 128;
    const float* Xb = X + (size_t)b * K * S;
    float* Ob = O + (size_t)b * M * S;

    const int t  = threadIdx.x;
    const int tm = t >> 4;    // 0..15 -> m block of 8
    const int tn = t & 15;    // 0..15 -> n: [tn*4, tn*4+4) and [64+tn*4, ...)

    __shared__ float As[16][132];
    __shared__ float Bs[16][132];

    float acc[8][8] = {};

    for (int k0 = 0; k0 < K; k0 += 16) {
        {
            const int m  = t >> 1;
            const int kk = (t & 1) * 8;
            const int row = m0 + m;
            float4 v0, v1;
            if (row < M) {
                const float* src = W + (size_t)row * K + k0 + kk;
                v0 = *(const float4*)(src);
                v1 = *(const float4*)(src + 4);
            } else {
                v0 = float4{0.f, 0.f, 0.f, 0.f};
                v1 = v0;
            }
            As[kk + 0][m] = v0.x; As[kk + 1][m] = v0.y;
            As[kk + 2][m] = v0.z; As[kk + 3][m] = v0.w;
            As[kk + 4][m] = v1.x; As[kk + 5][m] = v1.y;
            As[kk + 6][m] = v1.z; As[kk + 7][m] = v1.w;
        }
        {
            const int k = t >> 4;
            const int n = (t & 15) * 8;
            const float* src = Xb + (size_t)(k0 + k) * S + n0 + n;
            float4 v0 = *(const float4*)(src);
            float4 v1 = *(const float4*)(src + 4);
            *(float4*)&Bs[k][n]     = v0;
            *(float4*)&Bs[k][n + 4] = v1;
        }
        __syncthreads();

        #pragma unroll
        for (int k = 0; k < 16; k++) {
            float a[8], bb[8];
            *(float4*)&a[0]  = *(const float4*)&As[k][tm * 8];
            *(float4*)&a[4]  = *(const float4*)&As[k][tm * 8 + 4];
            *(float4*)&bb[0] = *(const float4*)&Bs[k][tn * 4];
            *(float4*)&bb[4] = *(const float4*)&Bs[k][64 + tn * 4];
            #pragma unroll
            for (int i = 0; i < 8; i++)
                #pragma unroll
                for (int j = 0; j < 8; j++)
                    acc[i][j] += a[i] * bb[j];
        }
        __syncthreads();
    }

    #pragma unroll
    for (int i = 0; i < 8; i++) {
        const int m = m0 + tm * 8 + i;
        if (m >= M) break;
        const float bv = bias ? bias[m] : 0.f;
        float* dst = Ob + (size_t)m * S + n0 + tn * 4;
        float r0[4], r1[4];
        #pragma unroll
        for (int j = 0; j < 4; j++) {
            float v = acc[i][j] + bv;
            if (relu) v = fmaxf(v, 0.f);
            r0[j] = v;
        }
        #pragma unroll
        for (int j = 0; j < 4; j++) {
            float v = acc[i][4 + j] + bv;
            if (relu) v = fmaxf(v, 0.f);
            r1[j] = v;
        }
        *(float4*)(dst)      = *(float4*)&r0[0];
        *(float4*)(dst + 64) = *(float4*)&r1[0];
    }
}

// ---------------------------------------------------------------------------
// Merged q/k FP64-accumulating GEMM, fp32 out. grid (32, 6, 16):
// z<8: q batch z (x, Wq -> Oq); z>=8: k batch z-8 (y, Wkv -> Ok).
// Tile 64(m)x128(n), K-step 16. Conflict-free B reads.
// ---------------------------------------------------------------------------
__global__ __launch_bounds__(256)
void gemm_qk_f64f(const float* __restrict__ x, const float* __restrict__ y,
                  const float* __restrict__ Wq, const float* __restrict__ Wkv,
                  float* __restrict__ Oq, float* __restrict__ Ok)
{
    const int z = blockIdx.z;
    const size_t plane = (size_t)CD * TS;
    const float* Xb = (z < 8) ? (x + (size_t)z * plane) : (y + (size_t)(z - 8) * plane);
    const float* W  = (z < 8) ? Wq : Wkv;
    float* Ob = (z < 8) ? (Oq + (size_t)z * plane) : (Ok + (size_t)(z - 8) * plane);

    const int m0 = blockIdx.y * 64;
    const int n0 = blockIdx.x * 128;
    const int t  = threadIdx.x;

    __shared__ float As[16][68];
    __shared__ float Bs[16][136];

    const int tm = t >> 4;      // 0..15 -> m block of 4
    const int tn = t & 15;      // 0..15 -> n: tn*4 and 64+tn*4

    double acc[4][8] = {};

    for (int k0 = 0; k0 < CD; k0 += 16) {
        {   // A: 64 m x 16 k
            const int m = t >> 2, kq = (t & 3) * 4;
            const float4 v = *(const float4*)(W + (size_t)(m0 + m) * CD + k0 + kq);
            As[kq + 0][m] = v.x; As[kq + 1][m] = v.y;
            As[kq + 2][m] = v.z; As[kq + 3][m] = v.w;
        }
        {   // B: 16 k x 128 n
            const int k = t >> 4, n8 = (t & 15) * 8;
            const float* src = Xb + (size_t)(k0 + k) * TS + n0 + n8;
            float4 v0 = *(const float4*)(src);
            float4 v1 = *(const float4*)(src + 4);
            *(float4*)&Bs[k][n8]     = v0;
            *(float4*)&Bs[k][n8 + 4] = v1;
        }
        __syncthreads();

        #pragma unroll
        for (int k = 0; k < 16; k++) {
            const float4 a4  = *(const float4*)&As[k][tm * 4];
            const float4 b40 = *(const float4*)&Bs[k][tn * 4];
            const float4 b41 = *(const float4*)&Bs[k][64 + tn * 4];
            const double a[4]  = {(double)a4.x, (double)a4.y, (double)a4.z, (double)a4.w};
            const double bb[8] = {(double)b40.x, (double)b40.y, (double)b40.z, (double)b40.w,
                                  (double)b41.x, (double)b41.y, (double)b41.z, (double)b41.w};
            #pragma unroll
            for (int i = 0; i < 4; i++)
                #pragma unroll
                for (int j = 0; j < 8; j++)
                    acc[i][j] += a[i] * bb[j];
        }
        __syncthreads();
    }

    #pragma unroll
    for (int i = 0; i < 4; i++) {
        const int m = m0 + tm * 4 + i;
        float* dst = Ob + (size_t)m * TS + n0 + tn * 4;
        float r0[4], r1[4];
        #pragma unroll
        for (int j = 0; j < 4; j++) r0[j] = (float)acc[i][j];
        #pragma unroll
        for (int j = 0; j < 4; j++) r1[j] = (float)acc[i][4 + j];
        *(float4*)(dst)      = *(float4*)&r0[0];
        *(float4*)(dst + 64) = *(float4*)&r1[0];
    }
}

// ---------------------------------------------------------------------------
// FP32 depthwise 3x3 SAME, batched over z. grid (16, C, nbatch).
// ---------------------------------------------------------------------------
__global__ __launch_bounds__(256)
void dw3x3(const float* __restrict__ X, const float* __restrict__ Wd,
           float* __restrict__ O, int C)
{
    const int b = blockIdx.z, c = blockIdx.y;
    const int s = blockIdx.x * 256 + threadIdx.x;
    const int yy0 = s >> 6, xx0 = s & 63;
    const float* Xc = X + ((size_t)b * C + c) * TS;
    const float* w  = Wd + (size_t)c * 9;
    float acc = 0.f;
    #pragma unroll
    for (int dy = -1; dy <= 1; dy++) {
        const int yy = yy0 + dy;
        if (yy < 0 || yy > 63) continue;
        #pragma unroll
        for (int dx = -1; dx <= 1; dx++) {
            const int xx = xx0 + dx;
            if (xx < 0 || xx > 63) continue;
            acc += Xc[yy * 64 + xx] * w[(dy + 1) * 3 + (dx + 1)];
        }
    }
    O[((size_t)b * C + c) * TS + s] = acc;
}

// ---------------------------------------------------------------------------
// Gate stage 2 on fp32 g1 planes [8][192][4096], fp64 dot + sigmoid,
// deterministic block sums. grid (16, 8).
// ---------------------------------------------------------------------------
__global__ __launch_bounds__(256)
void gate2p(const float* __restrict__ G0, const float* __restrict__ Wg2,
            const float* __restrict__ bg2, double* __restrict__ partial)
{
    const float* G = G0 + (size_t)blockIdx.y * 192 * TS;
    const int s = blockIdx.x * 256 + threadIdx.x;
    double z = (double)bg2[0];
    for (int c = 0; c < 192; c++)
        z += (double)Wg2[c] * (double)G[(size_t)c * TS + s];
    double sig = 1.0 / (1.0 + exp(-z));

    __shared__ double red[256];
    red[threadIdx.x] = sig;
    __syncthreads();
    for (int off = 128; off > 0; off >>= 1) {
        if ((int)threadIdx.x < off) red[threadIdx.x] += red[threadIdx.x + off];
        __syncthreads();
    }
    if (threadIdx.x == 0) partial[blockIdx.y * 16 + blockIdx.x] = red[0];
}

__global__ void gate_final(const double* __restrict__ partial, int n,
                           int* __restrict__ dkp)
{
    double s = 0.0;
    for (int i = 0; i < n; i++) s += partial[i];
    double mean = s / (double)(8 * TS);
    int dk = (int)floor((double)CPH * mean);
    dk = dk < 1 ? 1 : (dk > CPH ? CPH : dk);
    *dkp = dk;
}

// ---------------------------------------------------------------------------
// Row L2 norm over spatial (fp32 in, fp64 accum). Writes 1/max(norm,1e-12).
// ---------------------------------------------------------------------------
__global__ __launch_bounds__(256)
void rownorm(const float* __restrict__ X, double* __restrict__ inv)
{
    const int r = blockIdx.x;
    const float* p = X + (size_t)r * TS;
    double ss = 0.0;
    for (int i = threadIdx.x; i < TS; i += 256) {
        double v = (double)p[i]; ss += v * v;
    }
    __shared__ double red[256];
    red[threadIdx.x] = ss;
    __syncthreads();
    for (int off = 128; off > 0; off >>= 1) {
        if ((int)threadIdx.x < off) red[threadIdx.x] += red[threadIdx.x + off];
        __syncthreads();
    }
    if (threadIdx.x == 0) inv[r] = 1.0 / fmax(sqrt(red[0]), 1e-12);
}

// ---------------------------------------------------------------------------
// QK^T partial sums: grid (16 spatial chunks, 64 bh). fp64 partial 48x48.
// ---------------------------------------------------------------------------
__global__ __launch_bounds__(256)
void qkt_part(const float* __restrict__ QD, const float* __restrict__ KD,
              double* __restrict__ Spart)
{
    const int ci = blockIdx.x;   // 0..15
    const int bh = blockIdx.y;   // 0..63
    const int b = bh >> 3, h = bh & 7;
    const int t = threadIdx.x;

    const float* qp = QD + ((size_t)b * CD + h * CPH) * TS + ci * 256;
    const float* kp = KD + ((size_t)b * CD + h * CPH) * TS + ci * 256;

    __shared__ float qs[CPH][132];
    __shared__ float ks[CPH][132];

    const int cb = (t >> 4) * 3;   // 0..45
    const int db = (t & 15) * 3;   // 0..45

    double acc[3][3] = {};

    #pragma unroll
    for (int sub = 0; sub < 2; sub++) {
        for (int idx = t; idx < CPH * 32; idx += 256) {
            const int r = idx >> 5, c4 = (idx & 31) * 4;
            *(float4*)&qs[r][c4] = *(const float4*)(qp + (size_t)r * TS + sub * 128 + c4);
            *(float4*)&ks[r][c4] = *(const float4*)(kp + (size_t)r * TS + sub * 128 + c4);
        }
        __syncthreads();
        #pragma unroll 2
        for (int ss = 0; ss < 128; ss++) {
            const double a0 = qs[cb + 0][ss], a1 = qs[cb + 1][ss], a2 = qs[cb + 2][ss];
            const double b0 = ks[db + 0][ss], b1 = ks[db + 1][ss], b2 = ks[db + 2][ss];
            acc[0][0] += a0 * b0; acc[0][1] += a0 * b1; acc[0][2] += a0 * b2;
            acc[1][0] += a1 * b0; acc[1][1] += a1 * b1; acc[1][2] += a1 * b2;
            acc[2][0] += a2 * b0; acc[2][1] += a2 * b1; acc[2][2] += a2 * b2;
        }
        __syncthreads();
    }

    double* Sp = Spart + ((size_t)ci * 64 + bh) * (CPH * CPH);
    #pragma unroll
    for (int i = 0; i < 3; i++)
        #pragma unroll
        for (int j = 0; j < 3; j++)
            Sp[(cb + i) * CPH + db + j] = acc[i][j];
}

// ---------------------------------------------------------------------------
// Reduce partials in fixed chunk order, apply temp*invq*invk. grid 64.
// ---------------------------------------------------------------------------
__global__ __launch_bounds__(256)
void qkt_reduce(const double* __restrict__ Spart,
                const double* __restrict__ invq, const double* __restrict__ invk,
                const float* __restrict__ temperature, double* __restrict__ Sg)
{
    const int bh = blockIdx.x;
    const int b = bh >> 3, h = bh & 7;
    const int rowbase = b * CD + h * CPH;
    const double tmp = (double)temperature[h];
    for (int idx = threadIdx.x; idx < CPH * CPH; idx += 256) {
        const int c = idx / CPH, d = idx % CPH;
        double s = 0.0;
        for (int ci = 0; ci < 16; ci++)
            s += Spart[((size_t)ci * 64 + bh) * (CPH * CPH) + idx];
        Sg[(size_t)bh * CPH * CPH + idx] = s * invq[rowbase + c] * tmp * invk[rowbase + d];
    }
}

// ---------------------------------------------------------------------------
// Per-row dynamic top-k threshold (counting rank == sort+slice incl. ties)
// + softmax in fp64; float P written in place over this block's own region
// (per-bh stride stays 2*CPH*CPH floats for readers).
// ---------------------------------------------------------------------------
__global__ __launch_bounds__(64)
void topk_softmax(double* __restrict__ Sg, const int* __restrict__ dkp)
{
    const int bh = blockIdx.x;
    const int t = threadIdx.x;
    double* Sp = Sg + (size_t)bh * CPH * CPH;

    __shared__ double p[CPH][CPH + 1];
    for (int idx = t; idx < CPH * CPH; idx += 64)
        p[idx / CPH][idx % CPH] = Sp[idx];
    __syncthreads();

    if (t < CPH) {
        const int dk = *dkp;
        const int r = t;
        double thr = 0.0;
        for (int o = 0; o < CPH; o++) {
            const double v = p[r][o];
            int g = 0, ge = 0;
            for (int u = 0; u < CPH; u++) {
                const double w = p[r][u];
                g  += (w > v);
                ge += (w >= v);
            }
            if (g < dk && dk <= ge) thr = v;
        }
        double m = -INFINITY;
        for (int o = 0; o < CPH; o++) {
            const double v = p[r][o];
            if (v >= thr && v > m) m = v;
        }
        double sum = 0.0;
        for (int o = 0; o < CPH; o++) {
            const double v = p[r][o];
            const double e = (v >= thr) ? exp(v - m) : 0.0;
            p[r][o] = e;
            sum += e;
        }
        const double is = 1.0 / sum;
        float* outp = (float*)Sp;   // own region only; stride 2*CPH*CPH floats
        for (int o = 0; o < CPH; o++)
            outp[r * CPH + o] = (float)(p[r][o] * is);
    }
}

// ---------------------------------------------------------------------------
// out[c,s] = sum_d P[c,d] * V[d,s].  grid (16 s-chunks, 64 bh), 256 threads.
// Pg = float view of Sg; per-bh stride = 2*CPH*CPH floats.
// ---------------------------------------------------------------------------
__global__ __launch_bounds__(256)
void pv(const float* __restrict__ Pg, const float* __restrict__ VD,
        float* __restrict__ OAT)
{
    const int bh = blockIdx.y;
    const int b = bh >> 3, h = bh & 7;
    const int t = threadIdx.x;
    const int s = blockIdx.x * 256 + t;

    __shared__ float p[CPH][CPH + 1];
    const float* Sp = Pg + (size_t)bh * (2 * CPH * CPH);
    for (int idx = t; idx < CPH * CPH; idx += 256)
        p[idx / CPH][idx % CPH] = Sp[idx];
    __syncthreads();

    const float* vp = VD + ((size_t)b * CD + h * CPH) * TS;
    float* op = OAT + ((size_t)b * CD + h * CPH) * TS;

    float vv[CPH];
    #pragma unroll
    for (int d = 0; d < CPH; d++) vv[d] = vp[(size_t)d * TS + s];
    for (int c = 0; c < CPH; c++) {
        float o = 0.f;
        #pragma unroll
        for (int d = 0; d < CPH; d++) o += p[c][d] * vv[d];
        op[(size_t)c * TS + s] = o;
    }
}

// ---------------------------------------------------------------------------
extern "C" void kernel_launch(void* const* d_in, const int* in_sizes, int n_in,
                              void* d_out, int out_size, void* d_ws, size_t ws_size,
                              hipStream_t stream)
{
    const float* x     = (const float*)d_in[0];
    const float* y     = (const float*)d_in[1];
    const float* Wq    = (const float*)d_in[2];
    const float* Wqdw  = (const float*)d_in[3];
    const float* Wkv   = (const float*)d_in[4];
    const float* Wkvdw = (const float*)d_in[5];
    const float* Wproj = (const float*)d_in[6];
    const float* Wg1   = (const float*)d_in[7];
    const float* bg1   = (const float*)d_in[8];
    const float* Wg2   = (const float*)d_in[9];
    const float* bg2   = (const float*)d_in[10];
    const float* temp  = (const float*)d_in[11];
    float* out = (float*)d_out;

    const size_t BIG   = (size_t)8 * CD * TS * 4;       // 50,331,648
    const size_t SG_B  = (size_t)64 * CPH * CPH * 8;    // 1,179,648
    const size_t INV_B = 3072 * 8;
    const size_t NEEDED = 2 * BIG + SG_B + 2 * INV_B + 1024 + 16;
    if (ws_size < NEEDED) return;

    char* w = (char*)d_ws;
    float*  B1    = (float*)(w);                 // g1 -> q1x1 -> kd -> attnout
    float*  B2    = (float*)(w + BIG);           // k1x1 -> Spart -> v1x1
    double* Spart = (double*)(w + BIG);
    char* tail = w + 2 * BIG;
    double* Sg   = (double*)(tail);
    double* invq = (double*)(tail + SG_B);
    double* invk = (double*)(tail + SG_B + INV_B);
    double* part = (double*)(tail + SG_B + 2 * INV_B);
    int*    dkp  = (int*)(tail + SG_B + 2 * INV_B + 1024);

    const size_t planeF = (size_t)CD * TS;

    // ---- gate (fp32 GEMM is safe: dk margin-to-integer >> fp32 noise) ----
    gemm1x1<<<dim3(32, 2, 8), 256, 0, stream>>>(x, Wg1, bg1, B1, CD, 192, TS, 1);
    gate2p<<<dim3(16, 8), 256, 0, stream>>>(B1, Wg2, bg2, part);
    gate_final<<<1, 1, 0, stream>>>(part, 128, dkp);

    // ---- q & k 1x1 (fp64 accum) merged: q -> B1, k -> B2 ----
    gemm_qk_f64f<<<dim3(32, 6, 16), 256, 0, stream>>>(x, y, Wq, Wkv, B1, B2);

    // ---- depthwise: qd -> d_out, kd -> B1 (after q read done) ----
    dw3x3<<<dim3(16, CD, 8), 256, 0, stream>>>(B1, Wqdw, out, CD);
    dw3x3<<<dim3(16, CD, 8), 256, 0, stream>>>(B2, Wkvdw, B1, CD);

    // ---- norms + S (Spart in B2; k1x1 dead) ----
    rownorm<<<3072, 256, 0, stream>>>(out, invq);
    rownorm<<<3072, 256, 0, stream>>>(B1, invk);
    qkt_part<<<dim3(16, 64), 256, 0, stream>>>(out, B1, Spart);
    qkt_reduce<<<64, 256, 0, stream>>>(Spart, invq, invk, temp, Sg);

    // ---- top-k + softmax -> float P in place (Sg) ----
    topk_softmax<<<64, 64, 0, stream>>>(Sg, dkp);

    // ---- v path: v1x1 -> B2 (Spart dead), dw -> d_out (qd dead) ----
    gemm1x1<<<dim3(32, 3, 8), 256, 0, stream>>>(y, Wkv + (size_t)CD * CD, nullptr, B2, CD, CD, TS, 0);
    dw3x3<<<dim3(16, CD, 8), 256, 0, stream>>>(B2, Wkvdw + (size_t)CD * 9, out, CD);

    // ---- attn @ V -> B1 (kd dead) ----
    pv<<<dim3(16, 64), 256, 0, stream>>>((const float*)Sg, out, B1);

    // ---- projection -> d_out ----
    gemm1x1<<<dim3(32, 3, 8), 256, 0, stream>>>(B1, Wproj, nullptr, out, CD, CD, TS, 0);
}

// Round 8
// 968.217 us; speedup vs baseline: 2.4424x; 1.1451x over previous
//
#include <hip/hip_runtime.h>
#include <cstddef>
#include <cstdint>
#include <cmath>

#define TS 4096   // spatial size H*W (64*64)
#define CD 384    // channels
#define NHEADS 8
#define CPH 48    // channels per head

typedef __attribute__((ext_vector_type(8))) short bf16x8;
typedef __attribute__((ext_vector_type(4))) float f32x4;

__device__ __forceinline__ unsigned short f2bf(float f) {
    unsigned int u = __float_as_uint(f);
    u = u + 0x7FFF + ((u >> 16) & 1);   // RTNE
    return (unsigned short)(u >> 16);
}
__device__ __forceinline__ float bf2f(unsigned short s) {
    return __uint_as_float(((unsigned int)s) << 16);
}

// ---------------------------------------------------------------------------
// FP32 GEMM for 1x1 conv (gate path): O[b,m,s] = sum_k W[m,k] X[b,k,s]
// 128x128x16 tile, 256 thr, 8x8 micro, conflict-free B reads. Guards M=192.
// ---------------------------------------------------------------------------
__global__ __launch_bounds__(256)
void gemm1x1(const float* __restrict__ X, const float* __restrict__ W,
             const float* __restrict__ bias, float* __restrict__ O,
             int K, int M, int S, int relu)
{
    const int b  = blockIdx.z;
    const int m0 = blockIdx.y * 128;
    const int n0 = blockIdx.x * 128;
    const float* Xb = X + (size_t)b * K * S;
    float* Ob = O + (size_t)b * M * S;

    const int t  = threadIdx.x;
    const int tm = t >> 4;
    const int tn = t & 15;

    __shared__ float As[16][132];
    __shared__ float Bs[16][132];

    float acc[8][8] = {};

    for (int k0 = 0; k0 < K; k0 += 16) {
        {
            const int m  = t >> 1;
            const int kk = (t & 1) * 8;
            const int row = m0 + m;
            float4 v0, v1;
            if (row < M) {
                const float* src = W + (size_t)row * K + k0 + kk;
                v0 = *(const float4*)(src);
                v1 = *(const float4*)(src + 4);
            } else {
                v0 = float4{0.f, 0.f, 0.f, 0.f};
                v1 = v0;
            }
            As[kk + 0][m] = v0.x; As[kk + 1][m] = v0.y;
            As[kk + 2][m] = v0.z; As[kk + 3][m] = v0.w;
            As[kk + 4][m] = v1.x; As[kk + 5][m] = v1.y;
            As[kk + 6][m] = v1.z; As[kk + 7][m] = v1.w;
        }
        {
            const int k = t >> 4;
            const int n = (t & 15) * 8;
            const float* src = Xb + (size_t)(k0 + k) * S + n0 + n;
            float4 v0 = *(const float4*)(src);
            float4 v1 = *(const float4*)(src + 4);
            *(float4*)&Bs[k][n]     = v0;
            *(float4*)&Bs[k][n + 4] = v1;
        }
        __syncthreads();

        #pragma unroll
        for (int k = 0; k < 16; k++) {
            float a[8], bb[8];
            *(float4*)&a[0]  = *(const float4*)&As[k][tm * 8];
            *(float4*)&a[4]  = *(const float4*)&As[k][tm * 8 + 4];
            *(float4*)&bb[0] = *(const float4*)&Bs[k][tn * 4];
            *(float4*)&bb[4] = *(const float4*)&Bs[k][64 + tn * 4];
            #pragma unroll
            for (int i = 0; i < 8; i++)
                #pragma unroll
                for (int j = 0; j < 8; j++)
                    acc[i][j] += a[i] * bb[j];
        }
        __syncthreads();
    }

    #pragma unroll
    for (int i = 0; i < 8; i++) {
        const int m = m0 + tm * 8 + i;
        if (m >= M) break;
        const float bv = bias ? bias[m] : 0.f;
        float* dst = Ob + (size_t)m * S + n0 + tn * 4;
        float r0[4], r1[4];
        #pragma unroll
        for (int j = 0; j < 4; j++) {
            float v = acc[i][j] + bv;
            if (relu) v = fmaxf(v, 0.f);
            r0[j] = v;
        }
        #pragma unroll
        for (int j = 0; j < 4; j++) {
            float v = acc[i][4 + j] + bv;
            if (relu) v = fmaxf(v, 0.f);
            r1[j] = v;
        }
        *(float4*)(dst)      = *(float4*)&r0[0];
        *(float4*)(dst + 64) = *(float4*)&r1[0];
    }
}

// ---------------------------------------------------------------------------
// Merged q/k FP64-accumulating GEMM, fp32 out. grid (32, 3, 16).
// Tile 128(m)x128(n), K-step 16, 8x8 micro. Same k-order as before ->
// bitwise-identical q/k outputs.
// ---------------------------------------------------------------------------
__global__ __launch_bounds__(256)
void gemm_qk_f64f(const float* __restrict__ x, const float* __restrict__ y,
                  const float* __restrict__ Wq, const float* __restrict__ Wkv,
                  float* __restrict__ Oq, float* __restrict__ Ok)
{
    const int z = blockIdx.z;
    const size_t plane = (size_t)CD * TS;
    const float* Xb = (z < 8) ? (x + (size_t)z * plane) : (y + (size_t)(z - 8) * plane);
    const float* W  = (z < 8) ? Wq : Wkv;
    float* Ob = (z < 8) ? (Oq + (size_t)z * plane) : (Ok + (size_t)(z - 8) * plane);

    const int m0 = blockIdx.y * 128;
    const int n0 = blockIdx.x * 128;
    const int t  = threadIdx.x;
    const int tm = t >> 4;
    const int tn = t & 15;

    __shared__ float As[16][132];
    __shared__ float Bs[16][132];

    double acc[8][8] = {};

    for (int k0 = 0; k0 < CD; k0 += 16) {
        {   // A: 128 m x 16 k
            const int m = t >> 1, kk = (t & 1) * 8;
            const float* src = W + (size_t)(m0 + m) * CD + k0 + kk;
            float4 v0 = *(const float4*)(src);
            float4 v1 = *(const float4*)(src + 4);
            As[kk + 0][m] = v0.x; As[kk + 1][m] = v0.y;
            As[kk + 2][m] = v0.z; As[kk + 3][m] = v0.w;
            As[kk + 4][m] = v1.x; As[kk + 5][m] = v1.y;
            As[kk + 6][m] = v1.z; As[kk + 7][m] = v1.w;
        }
        {   // B: 16 k x 128 n
            const int k = t >> 4, n8 = (t & 15) * 8;
            const float* src = Xb + (size_t)(k0 + k) * TS + n0 + n8;
            float4 v0 = *(const float4*)(src);
            float4 v1 = *(const float4*)(src + 4);
            *(float4*)&Bs[k][n8]     = v0;
            *(float4*)&Bs[k][n8 + 4] = v1;
        }
        __syncthreads();

        #pragma unroll
        for (int k = 0; k < 16; k++) {
            const float4 a40 = *(const float4*)&As[k][tm * 8];
            const float4 a41 = *(const float4*)&As[k][tm * 8 + 4];
            const float4 b40 = *(const float4*)&Bs[k][tn * 4];
            const float4 b41 = *(const float4*)&Bs[k][64 + tn * 4];
            const double a[8]  = {(double)a40.x, (double)a40.y, (double)a40.z, (double)a40.w,
                                  (double)a41.x, (double)a41.y, (double)a41.z, (double)a41.w};
            const double bb[8] = {(double)b40.x, (double)b40.y, (double)b40.z, (double)b40.w,
                                  (double)b41.x, (double)b41.y, (double)b41.z, (double)b41.w};
            #pragma unroll
            for (int i = 0; i < 8; i++)
                #pragma unroll
                for (int j = 0; j < 8; j++)
                    acc[i][j] += a[i] * bb[j];
        }
        __syncthreads();
    }

    #pragma unroll
    for (int i = 0; i < 8; i++) {
        const int m = m0 + tm * 8 + i;
        float* dst = Ob + (size_t)m * TS + n0 + tn * 4;
        float r0[4], r1[4];
        #pragma unroll
        for (int j = 0; j < 4; j++) r0[j] = (float)acc[i][j];
        #pragma unroll
        for (int j = 0; j < 4; j++) r1[j] = (float)acc[i][4 + j];
        *(float4*)(dst)      = *(float4*)&r0[0];
        *(float4*)(dst + 64) = *(float4*)&r1[0];
    }
}

// ---------------------------------------------------------------------------
// Transpose + bf16 2-term split: X [b][C][S] fp32 -> Th/Tl [b][S][C] bf16.
// grid (S/64, C/64, 8), 256 thr, 64x64 tiles via LDS.
// ---------------------------------------------------------------------------
__global__ __launch_bounds__(256)
void tsplit(const float* __restrict__ X, unsigned short* __restrict__ Th,
            unsigned short* __restrict__ Tl)
{
    const int b  = blockIdx.z;
    const int c0 = blockIdx.y * 64;
    const int s0 = blockIdx.x * 64;
    const int t  = threadIdx.x;

    __shared__ float tile[64][65];

    {
        const int c = t >> 2, sq = (t & 3) * 16;
        const float* src = X + ((size_t)b * CD + c0 + c) * TS + s0 + sq;
        #pragma unroll
        for (int j = 0; j < 4; j++) {
            float4 v = *(const float4*)(src + j * 4);
            tile[c][sq + j * 4 + 0] = v.x;
            tile[c][sq + j * 4 + 1] = v.y;
            tile[c][sq + j * 4 + 2] = v.z;
            tile[c][sq + j * 4 + 3] = v.w;
        }
    }
    __syncthreads();
    {
        const int s = t >> 2, cq = (t & 3) * 16;
        unsigned short hb[16], lb[16];
        #pragma unroll
        for (int j = 0; j < 16; j++) {
            float f = tile[cq + j][s];
            unsigned short h = f2bf(f);
            hb[j] = h;
            lb[j] = f2bf(f - bf2f(h));
        }
        unsigned short* dh = Th + ((size_t)b * TS + s0 + s) * CD + c0 + cq;
        unsigned short* dl = Tl + ((size_t)b * TS + s0 + s) * CD + c0 + cq;
        *(uint4*)(dh)     = *(uint4*)&hb[0];
        *(uint4*)(dh + 8) = *(uint4*)&hb[8];
        *(uint4*)(dl)     = *(uint4*)&lb[0];
        *(uint4*)(dl + 8) = *(uint4*)&lb[8];
    }
}

// ---------------------------------------------------------------------------
// Weight bf16 2-term split (no transpose; W already k-contiguous). grid 576.
// ---------------------------------------------------------------------------
__global__ __launch_bounds__(256)
void wsplit(const float* __restrict__ W, unsigned short* __restrict__ Wh,
            unsigned short* __restrict__ Wl)
{
    const int i = blockIdx.x * 256 + threadIdx.x;
    const float f = W[i];
    const unsigned short h = f2bf(f);
    Wh[i] = h;
    Wl[i] = f2bf(f - bf2f(h));
}

// ---------------------------------------------------------------------------
// Split-bf16 MFMA GEMM: O[b][m][s] = sum_k W[m,k] X[k,s], inputs pre-split.
// 128x128 tile, BK=32, 4 waves (2x2, 64x64 each), 16x16x32 bf16 MFMA,
// 3 products (hh, hl, lh). M must be multiple of 128.
// ---------------------------------------------------------------------------
__global__ __launch_bounds__(256)
void gemm_mfma2(const unsigned short* __restrict__ Th,
                const unsigned short* __restrict__ Tl,
                const unsigned short* __restrict__ Wh,
                const unsigned short* __restrict__ Wl,
                float* __restrict__ O, int M)
{
    const int b  = blockIdx.z;
    const int m0 = blockIdx.y * 128;
    const int n0 = blockIdx.x * 128;
    const int t  = threadIdx.x;
    const int l  = t & 63;
    const int wv = t >> 6;
    const int wm = (wv & 1) * 64;
    const int wn = (wv >> 1) * 64;
    const int lr = l & 15;
    const int lg = l >> 4;

    __shared__ unsigned short Ah[128][40];
    __shared__ unsigned short Al[128][40];
    __shared__ unsigned short Bh[128][40];
    __shared__ unsigned short Bl[128][40];

    f32x4 acc[4][4];
    #pragma unroll
    for (int i = 0; i < 4; i++)
        #pragma unroll
        for (int j = 0; j < 4; j++)
            acc[i][j] = (f32x4){0.f, 0.f, 0.f, 0.f};

    const int srow = t >> 1;
    const int kh   = (t & 1) * 16;
    const unsigned short* wh = Wh + (size_t)(m0 + srow) * CD + kh;
    const unsigned short* wl = Wl + (size_t)(m0 + srow) * CD + kh;
    const unsigned short* xh = Th + ((size_t)b * TS + n0 + srow) * CD + kh;
    const unsigned short* xl = Tl + ((size_t)b * TS + n0 + srow) * CD + kh;

    for (int k0 = 0; k0 < CD; k0 += 32) {
        *(uint4*)&Ah[srow][kh]     = *(const uint4*)(wh + k0);
        *(uint4*)&Ah[srow][kh + 8] = *(const uint4*)(wh + k0 + 8);
        *(uint4*)&Al[srow][kh]     = *(const uint4*)(wl + k0);
        *(uint4*)&Al[srow][kh + 8] = *(const uint4*)(wl + k0 + 8);
        *(uint4*)&Bh[srow][kh]     = *(const uint4*)(xh + k0);
        *(uint4*)&Bh[srow][kh + 8] = *(const uint4*)(xh + k0 + 8);
        *(uint4*)&Bl[srow][kh]     = *(const uint4*)(xl + k0);
        *(uint4*)&Bl[srow][kh + 8] = *(const uint4*)(xl + k0 + 8);
        __syncthreads();

        bf16x8 fah[4], fal[4], fbh[4], fbl[4];
        #pragma unroll
        for (int i = 0; i < 4; i++) {
            fah[i] = *(const bf16x8*)&Ah[wm + i * 16 + lr][lg * 8];
            fal[i] = *(const bf16x8*)&Al[wm + i * 16 + lr][lg * 8];
            fbh[i] = *(const bf16x8*)&Bh[wn + i * 16 + lr][lg * 8];
            fbl[i] = *(const bf16x8*)&Bl[wn + i * 16 + lr][lg * 8];
        }
        #pragma unroll
        for (int i = 0; i < 4; i++)
            #pragma unroll
            for (int j = 0; j < 4; j++) {
                acc[i][j] = __builtin_amdgcn_mfma_f32_16x16x32_bf16(fah[i], fbh[j], acc[i][j], 0, 0, 0);
                acc[i][j] = __builtin_amdgcn_mfma_f32_16x16x32_bf16(fah[i], fbl[j], acc[i][j], 0, 0, 0);
                acc[i][j] = __builtin_amdgcn_mfma_f32_16x16x32_bf16(fal[i], fbh[j], acc[i][j], 0, 0, 0);
            }
        __syncthreads();
    }

    float* Ob = O + ((size_t)b * M + m0) * TS + n0;
    #pragma unroll
    for (int i = 0; i < 4; i++) {
        #pragma unroll
        for (int r = 0; r < 4; r++) {
            const int m = wm + i * 16 + lg * 4 + r;
            float* dst = Ob + (size_t)m * TS + wn + lr;
            #pragma unroll
            for (int j = 0; j < 4; j++)
                dst[j * 16] = acc[i][j][r];
        }
    }
}

// ---------------------------------------------------------------------------
// FP32 depthwise 3x3 SAME, batched over z. grid (16, C, nbatch).
// ---------------------------------------------------------------------------
__global__ __launch_bounds__(256)
void dw3x3(const float* __restrict__ X, const float* __restrict__ Wd,
           float* __restrict__ O, int C)
{
    const int b = blockIdx.z, c = blockIdx.y;
    const int s = blockIdx.x * 256 + threadIdx.x;
    const int yy0 = s >> 6, xx0 = s & 63;
    const float* Xc = X + ((size_t)b * C + c) * TS;
    const float* w  = Wd + (size_t)c * 9;
    float acc = 0.f;
    #pragma unroll
    for (int dy = -1; dy <= 1; dy++) {
        const int yy = yy0 + dy;
        if (yy < 0 || yy > 63) continue;
        #pragma unroll
        for (int dx = -1; dx <= 1; dx++) {
            const int xx = xx0 + dx;
            if (xx < 0 || xx > 63) continue;
            acc += Xc[yy * 64 + xx] * w[(dy + 1) * 3 + (dx + 1)];
        }
    }
    O[((size_t)b * C + c) * TS + s] = acc;
}

// ---------------------------------------------------------------------------
// Gate stage 2: fp64 dot + sigmoid, deterministic block sums. grid (16, 8).
// ---------------------------------------------------------------------------
__global__ __launch_bounds__(256)
void gate2p(const float* __restrict__ G0, const float* __restrict__ Wg2,
            const float* __restrict__ bg2, double* __restrict__ partial)
{
    const float* G = G0 + (size_t)blockIdx.y * 192 * TS;
    const int s = blockIdx.x * 256 + threadIdx.x;
    double z = (double)bg2[0];
    for (int c = 0; c < 192; c++)
        z += (double)Wg2[c] * (double)G[(size_t)c * TS + s];
    double sig = 1.0 / (1.0 + exp(-z));

    __shared__ double red[256];
    red[threadIdx.x] = sig;
    __syncthreads();
    for (int off = 128; off > 0; off >>= 1) {
        if ((int)threadIdx.x < off) red[threadIdx.x] += red[threadIdx.x + off];
        __syncthreads();
    }
    if (threadIdx.x == 0) partial[blockIdx.y * 16 + blockIdx.x] = red[0];
}

__global__ void gate_final(const double* __restrict__ partial, int n,
                           int* __restrict__ dkp)
{
    double s = 0.0;
    for (int i = 0; i < n; i++) s += partial[i];
    double mean = s / (double)(8 * TS);
    int dk = (int)floor((double)CPH * mean);
    dk = dk < 1 ? 1 : (dk > CPH ? CPH : dk);
    *dkp = dk;
}

// ---------------------------------------------------------------------------
// Row L2 norm over spatial (fp32 in, fp64 accum). Writes 1/max(norm,1e-12).
// ---------------------------------------------------------------------------
__global__ __launch_bounds__(256)
void rownorm(const float* __restrict__ X, double* __restrict__ inv)
{
    const int r = blockIdx.x;
    const float* p = X + (size_t)r * TS;
    double ss = 0.0;
    for (int i = threadIdx.x; i < TS; i += 256) {
        double v = (double)p[i]; ss += v * v;
    }
    __shared__ double red[256];
    red[threadIdx.x] = ss;
    __syncthreads();
    for (int off = 128; off > 0; off >>= 1) {
        if ((int)threadIdx.x < off) red[threadIdx.x] += red[threadIdx.x + off];
        __syncthreads();
    }
    if (threadIdx.x == 0) inv[r] = 1.0 / fmax(sqrt(red[0]), 1e-12);
}

// ---------------------------------------------------------------------------
// QK^T partial sums: grid (16 spatial chunks, 64 bh). fp64 partial 48x48.
// ---------------------------------------------------------------------------
__global__ __launch_bounds__(256)
void qkt_part(const float* __restrict__ QD, const float* __restrict__ KD,
              double* __restrict__ Spart)
{
    const int ci = blockIdx.x;
    const int bh = blockIdx.y;
    const int b = bh >> 3, h = bh & 7;
    const int t = threadIdx.x;

    const float* qp = QD + ((size_t)b * CD + h * CPH) * TS + ci * 256;
    const float* kp = KD + ((size_t)b * CD + h * CPH) * TS + ci * 256;

    __shared__ float qs[CPH][132];
    __shared__ float ks[CPH][132];

    const int cb = (t >> 4) * 3;
    const int db = (t & 15) * 3;

    double acc[3][3] = {};

    #pragma unroll
    for (int sub = 0; sub < 2; sub++) {
        for (int idx = t; idx < CPH * 32; idx += 256) {
            const int r = idx >> 5, c4 = (idx & 31) * 4;
            *(float4*)&qs[r][c4] = *(const float4*)(qp + (size_t)r * TS + sub * 128 + c4);
            *(float4*)&ks[r][c4] = *(const float4*)(kp + (size_t)r * TS + sub * 128 + c4);
        }
        __syncthreads();
        #pragma unroll 2
        for (int ss = 0; ss < 128; ss++) {
            const double a0 = qs[cb + 0][ss], a1 = qs[cb + 1][ss], a2 = qs[cb + 2][ss];
            const double b0 = ks[db + 0][ss], b1 = ks[db + 1][ss], b2 = ks[db + 2][ss];
            acc[0][0] += a0 * b0; acc[0][1] += a0 * b1; acc[0][2] += a0 * b2;
            acc[1][0] += a1 * b0; acc[1][1] += a1 * b1; acc[1][2] += a1 * b2;
            acc[2][0] += a2 * b0; acc[2][1] += a2 * b1; acc[2][2] += a2 * b2;
        }
        __syncthreads();
    }

    double* Sp = Spart + ((size_t)ci * 64 + bh) * (CPH * CPH);
    #pragma unroll
    for (int i = 0; i < 3; i++)
        #pragma unroll
        for (int j = 0; j < 3; j++)
            Sp[(cb + i) * CPH + db + j] = acc[i][j];
}

// ---------------------------------------------------------------------------
// Reduce partials in fixed chunk order, apply temp*invq*invk. grid 64.
// ---------------------------------------------------------------------------
__global__ __launch_bounds__(256)
void qkt_reduce(const double* __restrict__ Spart,
                const double* __restrict__ invq, const double* __restrict__ invk,
                const float* __restrict__ temperature, double* __restrict__ Sg)
{
    const int bh = blockIdx.x;
    const int b = bh >> 3, h = bh & 7;
    const int rowbase = b * CD + h * CPH;
    const double tmp = (double)temperature[h];
    for (int idx = threadIdx.x; idx < CPH * CPH; idx += 256) {
        const int c = idx / CPH, d = idx % CPH;
        double s = 0.0;
        for (int ci = 0; ci < 16; ci++)
            s += Spart[((size_t)ci * 64 + bh) * (CPH * CPH) + idx];
        Sg[(size_t)bh * CPH * CPH + idx] = s * invq[rowbase + c] * tmp * invk[rowbase + d];
    }
}

// ---------------------------------------------------------------------------
// Per-row dynamic top-k threshold + softmax (fp64); float P in place.
// ---------------------------------------------------------------------------
__global__ __launch_bounds__(64)
void topk_softmax(double* __restrict__ Sg, const int* __restrict__ dkp)
{
    const int bh = blockIdx.x;
    const int t = threadIdx.x;
    double* Sp = Sg + (size_t)bh * CPH * CPH;

    __shared__ double p[CPH][CPH + 1];
    for (int idx = t; idx < CPH * CPH; idx += 64)
        p[idx / CPH][idx % CPH] = Sp[idx];
    __syncthreads();

    if (t < CPH) {
        const int dk = *dkp;
        const int r = t;
        double thr = 0.0;
        for (int o = 0; o < CPH; o++) {
            const double v = p[r][o];
            int g = 0, ge = 0;
            for (int u = 0; u < CPH; u++) {
                const double w = p[r][u];
                g  += (w > v);
                ge += (w >= v);
            }
            if (g < dk && dk <= ge) thr = v;
        }
        double m = -INFINITY;
        for (int o = 0; o < CPH; o++) {
            const double v = p[r][o];
            if (v >= thr && v > m) m = v;
        }
        double sum = 0.0;
        for (int o = 0; o < CPH; o++) {
            const double v = p[r][o];
            const double e = (v >= thr) ? exp(v - m) : 0.0;
            p[r][o] = e;
            sum += e;
        }
        const double is = 1.0 / sum;
        float* outp = (float*)Sp;
        for (int o = 0; o < CPH; o++)
            outp[r * CPH + o] = (float)(p[r][o] * is);
    }
}

// ---------------------------------------------------------------------------
// out[c,s] = sum_d P[c,d] * V[d,s].  grid (16, 64), 256 threads.
// Pg = float view of Sg; per-bh stride = 2*CPH*CPH floats.
// ---------------------------------------------------------------------------
__global__ __launch_bounds__(256)
void pv(const float* __restrict__ Pg, const float* __restrict__ VD,
        float* __restrict__ OAT)
{
    const int bh = blockIdx.y;
    const int b = bh >> 3, h = bh & 7;
    const int t = threadIdx.x;
    const int s = blockIdx.x * 256 + t;

    __shared__ float p[CPH][CPH + 1];
    const float* Sp = Pg + (size_t)bh * (2 * CPH * CPH);
    for (int idx = t; idx < CPH * CPH; idx += 256)
        p[idx / CPH][idx % CPH] = Sp[idx];
    __syncthreads();

    const float* vp = VD + ((size_t)b * CD + h * CPH) * TS;
    float* op = OAT + ((size_t)b * CD + h * CPH) * TS;

    float vv[CPH];
    #pragma unroll
    for (int d = 0; d < CPH; d++) vv[d] = vp[(size_t)d * TS + s];
    for (int c = 0; c < CPH; c++) {
        float o = 0.f;
        #pragma unroll
        for (int d = 0; d < CPH; d++) o += p[c][d] * vv[d];
        op[(size_t)c * TS + s] = o;
    }
}

// ---------------------------------------------------------------------------
extern "C" void kernel_launch(void* const* d_in, const int* in_sizes, int n_in,
                              void* d_out, int out_size, void* d_ws, size_t ws_size,
                              hipStream_t stream)
{
    const float* x     = (const float*)d_in[0];
    const float* y     = (const float*)d_in[1];
    const float* Wq    = (const float*)d_in[2];
    const float* Wqdw  = (const float*)d_in[3];
    const float* Wkv   = (const float*)d_in[4];
    const float* Wkvdw = (const float*)d_in[5];
    const float* Wproj = (const float*)d_in[6];
    const float* Wg1   = (const float*)d_in[7];
    const float* bg1   = (const float*)d_in[8];
    const float* Wg2   = (const float*)d_in[9];
    const float* bg2   = (const float*)d_in[10];
    const float* temp  = (const float*)d_in[11];
    float* out = (float*)d_out;

    const size_t BIG    = (size_t)8 * CD * TS * 4;      // 50,331,648
    const size_t SG_B   = (size_t)64 * CPH * CPH * 8;   // 1,179,648
    const size_t INV_B  = 3072 * 8;                     // 24,576
    const size_t WSPL_B = (size_t)CD * CD * 2;          // 294,912 (one bf16 W matrix)
    const size_t TAIL_B = SG_B + 2 * INV_B + 1024 + 64 + 4 * WSPL_B;
    const size_t NEEDED = 2 * BIG + TAIL_B;
    if (ws_size < NEEDED) return;

    char* w = (char*)d_ws;
    float*  B1    = (float*)(w);                 // g1 -> q1x1 -> kd -> v1x1 -> attnout
    float*  B2    = (float*)(w + BIG);           // k1x1 -> Spart -> Th/Tl
    double* Spart = (double*)(w + BIG);
    unsigned short* Th = (unsigned short*)(w + BIG);
    unsigned short* Tl = Th + (size_t)8 * TS * CD;

    char* tail = w + 2 * BIG;
    double* Sg   = (double*)(tail);
    double* invq = (double*)(tail + SG_B);
    double* invk = (double*)(tail + SG_B + INV_B);
    double* part = (double*)(tail + SG_B + 2 * INV_B);
    int*    dkp  = (int*)(tail + SG_B + 2 * INV_B + 1024);
    unsigned short* Whv = (unsigned short*)(tail + SG_B + 2 * INV_B + 1024 + 64);
    unsigned short* Wlv = Whv + (size_t)CD * CD;
    unsigned short* Whp = Wlv + (size_t)CD * CD;
    unsigned short* Wlp = Whp + (size_t)CD * CD;

    // ---- weight splits (tiny, once) ----
    wsplit<<<576, 256, 0, stream>>>(Wkv + (size_t)CD * CD, Whv, Wlv);
    wsplit<<<576, 256, 0, stream>>>(Wproj, Whp, Wlp);

    // ---- gate (fp32 GEMM; dk margin >> fp32 noise, proven r6) ----
    gemm1x1<<<dim3(32, 2, 8), 256, 0, stream>>>(x, Wg1, bg1, B1, CD, 192, TS, 1);
    gate2p<<<dim3(16, 8), 256, 0, stream>>>(B1, Wg2, bg2, part);
    gate_final<<<1, 1, 0, stream>>>(part, 128, dkp);

    // ---- q & k 1x1 (fp64 accum, bitwise same as r7): q -> B1, k -> B2 ----
    gemm_qk_f64f<<<dim3(32, 3, 16), 256, 0, stream>>>(x, y, Wq, Wkv, B1, B2);

    // ---- depthwise: qd -> d_out, kd -> B1 ----
    dw3x3<<<dim3(16, CD, 8), 256, 0, stream>>>(B1, Wqdw, out, CD);
    dw3x3<<<dim3(16, CD, 8), 256, 0, stream>>>(B2, Wkvdw, B1, CD);

    // ---- norms + S (Spart in B2; k1x1 dead) ----
    rownorm<<<3072, 256, 0, stream>>>(out, invq);
    rownorm<<<3072, 256, 0, stream>>>(B1, invk);
    qkt_part<<<dim3(16, 64), 256, 0, stream>>>(out, B1, Spart);
    qkt_reduce<<<64, 256, 0, stream>>>(Spart, invq, invk, temp, Sg);

    // ---- top-k + softmax -> float P in place (Sg) ----
    topk_softmax<<<64, 64, 0, stream>>>(Sg, dkp);

    // ---- v path via MFMA: split y -> B2, GEMM -> B1 (kd dead), dw -> out ----
    tsplit<<<dim3(64, 6, 8), 256, 0, stream>>>(y, Th, Tl);
    gemm_mfma2<<<dim3(32, 3, 8), 256, 0, stream>>>(Th, Tl, Whv, Wlv, B1, CD);
    dw3x3<<<dim3(16, CD, 8), 256, 0, stream>>>(B1, Wkvdw + (size_t)CD * 9, out, CD);

    // ---- attn @ V -> B1 (v1x1 dead) ----
    pv<<<dim3(16, 64), 256, 0, stream>>>((const float*)Sg, out, B1);

    // ---- projection via MFMA: split attnout -> B2, GEMM -> d_out ----
    tsplit<<<dim3(64, 6, 8), 256, 0, stream>>>(B1, Th, Tl);
    gemm_mfma2<<<dim3(32, 3, 8), 256, 0, stream>>>(Th, Tl, Whp, Wlp, out, CD);
}